// Round 1
// baseline (373.600 us; speedup 1.0000x reference)
//
#include <hip/hip_runtime.h>
#include <stdint.h>

#define B_  2
#define S_  2048
#define D_  1024
#define H_  16
#define HD_ 64

typedef __attribute__((ext_vector_type(8))) short short8;
typedef __attribute__((ext_vector_type(4))) float f32x4;

__device__ inline unsigned short f2bf(float f) {
  union { float f; unsigned int i; } u; u.f = f;
  unsigned int r = u.i + 0x7FFFu + ((u.i >> 16) & 1u);   // RNE
  return (unsigned short)(r >> 16);
}

__device__ inline void gload16(const void* g, void* l) {
  __builtin_amdgcn_global_load_lds(
      (const __attribute__((address_space(1))) void*)g,
      (__attribute__((address_space(3))) void*)l,
      16, 0, 0);
}

// ---------------- cast x (f32 -> bf16), vectorized x4 ----------------
__global__ void cast_kernel(const float* __restrict__ in,
                            unsigned short* __restrict__ out, int n) {
  int i = (blockIdx.x * blockDim.x + threadIdx.x) * 4;
  if (i >= n) return;
  float4 v = *(const float4*)(in + i);
  union { unsigned short s[4]; uint2 v; } o;
  o.s[0] = f2bf(v.x); o.s[1] = f2bf(v.y); o.s[2] = f2bf(v.z); o.s[3] = f2bf(v.w);
  *(uint2*)(out + i) = o.v;
}

// ---------------- transpose + cast: in[R][C] f32 -> out[C][R] bf16 ----------------
__global__ void transpose_cast_kernel(const float* __restrict__ in,
                                      unsigned short* __restrict__ out,
                                      int R, int C) {
  __shared__ float tile[32][33];
  int bx = blockIdx.x, by = blockIdx.y;
  int tx = threadIdx.x, ty = threadIdx.y;   // block (32,8)
#pragma unroll
  for (int i = 0; i < 4; ++i)
    tile[ty + i * 8][tx] = in[(size_t)(by * 32 + ty + i * 8) * C + bx * 32 + tx];
  __syncthreads();
#pragma unroll
  for (int i = 0; i < 4; ++i)
    out[(size_t)(bx * 32 + ty + i * 8) * R + by * 32 + tx] = f2bf(tile[tx][ty + i * 8]);
}

// ---------------- bf16 GEMM, 128x128 tile, BK=32, m97 structure ----------------
// A[M][K] row-major bf16, Bt[N][K] row-major bf16 (i.e. B transposed).
// MODE 0: QKV epilogue -> q[b,h,s,hd], k[b,h,s,hd], vT[b,h,hd,s], all bf16
// MODE 1: out[i][j] = acc + bias[j], fp32
template <int MODE>
__global__ __launch_bounds__(256)
void gemm_bf16(const unsigned short* __restrict__ A,
               const unsigned short* __restrict__ Bt,
               int K,
               unsigned short* __restrict__ qw,
               unsigned short* __restrict__ kw,
               unsigned short* __restrict__ vTw,
               float* __restrict__ out,
               const float* __restrict__ bias) {
  __shared__ __align__(16) unsigned short As[128 * 32];
  __shared__ __align__(16) unsigned short Bs[128 * 32];
  const int t  = threadIdx.x;
  const int w  = t >> 6, l = t & 63;
  const int lr = l & 15, lg = l >> 4;
  const int wr = w >> 1, wc = w & 1;
  const int bn = blockIdx.x, bm = blockIdx.y;
  const int trow = t >> 2, tcol = (t & 3) << 3;

  const unsigned short* Ab = A  + (size_t)(bm * 128 + trow) * K + tcol;
  const unsigned short* Bb = Bt + (size_t)(bn * 128 + trow) * K + tcol;

  f32x4 acc[4][4];
#pragma unroll
  for (int m = 0; m < 4; ++m)
#pragma unroll
    for (int n = 0; n < 4; ++n)
      acc[m][n] = (f32x4){0.f, 0.f, 0.f, 0.f};

  for (int kt = 0; kt < K; kt += 32) {
    gload16(Ab + kt,          &As[(size_t)t * 8]);
    gload16(Ab + 64 * K + kt, &As[(size_t)(256 + t) * 8]);
    gload16(Bb + kt,          &Bs[(size_t)t * 8]);
    gload16(Bb + 64 * K + kt, &Bs[(size_t)(256 + t) * 8]);
    __syncthreads();
    short8 af[4], bf[4];
#pragma unroll
    for (int m = 0; m < 4; ++m)
      af[m] = *(const short8*)&As[(wr * 64 + m * 16 + lr) * 32 + lg * 8];
#pragma unroll
    for (int n = 0; n < 4; ++n)
      bf[n] = *(const short8*)&Bs[(wc * 64 + n * 16 + lr) * 32 + lg * 8];
#pragma unroll
    for (int m = 0; m < 4; ++m)
#pragma unroll
      for (int n = 0; n < 4; ++n)
        acc[m][n] = __builtin_amdgcn_mfma_f32_16x16x32_bf16(af[m], bf[n], acc[m][n], 0, 0, 0);
    __syncthreads();
  }

#pragma unroll
  for (int m = 0; m < 4; ++m)
#pragma unroll
    for (int n = 0; n < 4; ++n)
#pragma unroll
      for (int r = 0; r < 4; ++r) {
        float v = acc[m][n][r];
        int i = bm * 128 + wr * 64 + m * 16 + lg * 4 + r;
        int j = bn * 128 + wc * 64 + n * 16 + lr;
        if (MODE == 0) {
          unsigned short bv = f2bf(v);
          int b = i >> 11, s = i & 2047;
          int part = j >> 10, rem = j & 1023, h = rem >> 6, hd = rem & 63;
          size_t bh = (size_t)(b * H_ + h);
          if (part == 0)      qw[(bh * S_ + s) * HD_ + hd] = bv;
          else if (part == 1) kw[(bh * S_ + s) * HD_ + hd] = bv;
          else                vTw[(bh * HD_ + hd) * S_ + s] = bv;
        } else {
          out[(size_t)i * D_ + j] = v + bias[j];
        }
      }
}

// ---------------- flash attention: 128 q-rows/block, 4 waves x 32 rows ----------------
__global__ __launch_bounds__(256)
void attn_kernel(const unsigned short* __restrict__ qw,
                 const unsigned short* __restrict__ kw,
                 const unsigned short* __restrict__ vTw,
                 unsigned short* __restrict__ attn) {
  __shared__ __align__(16) unsigned short P[4][32][136];  // per-wave P tile, padded
  const int t  = threadIdx.x;
  const int w  = t >> 6, l = t & 63;
  const int lr = l & 15, lg = l >> 4;
  const int blk = blockIdx.x;
  const int bh = blk >> 4, qt = blk & 15;
  const int q0 = qt * 128 + w * 32;
  const unsigned short* Qb = qw  + (size_t)bh * S_ * HD_;
  const unsigned short* Kb = kw  + (size_t)bh * S_ * HD_;
  const unsigned short* Vb = vTw + (size_t)bh * HD_ * S_;

  // Q fragments held in registers for the whole kernel
  short8 qf[2][2];
#pragma unroll
  for (int m = 0; m < 2; ++m)
#pragma unroll
    for (int ks = 0; ks < 2; ++ks)
      qf[m][ks] = *(const short8*)&Qb[(size_t)(q0 + m * 16 + lr) * HD_ + ks * 32 + lg * 8];

  f32x4 of[2][4];
  float mrun[2][4], lrun[2][4];
#pragma unroll
  for (int m = 0; m < 2; ++m) {
#pragma unroll
    for (int n = 0; n < 4; ++n) of[m][n] = (f32x4){0.f, 0.f, 0.f, 0.f};
#pragma unroll
    for (int r = 0; r < 4; ++r) { mrun[m][r] = -1e30f; lrun[m][r] = 0.f; }
  }

  for (int kt = 0; kt < S_; kt += 128) {
    // S = Q K^T (scaled later); S-tile 32x128 per wave
    f32x4 sf[2][8];
#pragma unroll
    for (int m = 0; m < 2; ++m)
#pragma unroll
      for (int n = 0; n < 8; ++n) sf[m][n] = (f32x4){0.f, 0.f, 0.f, 0.f};
#pragma unroll
    for (int ks = 0; ks < 2; ++ks) {
#pragma unroll
      for (int n = 0; n < 8; ++n) {
        short8 kf = *(const short8*)&Kb[(size_t)(kt + n * 16 + lr) * HD_ + ks * 32 + lg * 8];
        sf[0][n] = __builtin_amdgcn_mfma_f32_16x16x32_bf16(qf[0][ks], kf, sf[0][n], 0, 0, 0);
        sf[1][n] = __builtin_amdgcn_mfma_f32_16x16x32_bf16(qf[1][ks], kf, sf[1][n], 0, 0, 0);
      }
    }
    // online softmax (rows live in (lg,r); 16 cols per frag in lr lanes)
#pragma unroll
    for (int m = 0; m < 2; ++m)
#pragma unroll
      for (int r = 0; r < 4; ++r) {
        float mx = -1e30f;
#pragma unroll
        for (int n = 0; n < 8; ++n) {
          sf[m][n][r] *= 0.125f;                 // 1/sqrt(64)
          mx = fmaxf(mx, sf[m][n][r]);
        }
        mx = fmaxf(mx, __shfl_xor(mx, 1));
        mx = fmaxf(mx, __shfl_xor(mx, 2));
        mx = fmaxf(mx, __shfl_xor(mx, 4));
        mx = fmaxf(mx, __shfl_xor(mx, 8));
        float mo = mrun[m][r];
        float mn = fmaxf(mo, mx);
        mrun[m][r] = mn;
        float alpha = __expf(mo - mn);
        float ts = 0.f;
#pragma unroll
        for (int n = 0; n < 8; ++n) {
          float p = __expf(sf[m][n][r] - mn);
          sf[m][n][r] = p;
          ts += p;
        }
        ts += __shfl_xor(ts, 1);
        ts += __shfl_xor(ts, 2);
        ts += __shfl_xor(ts, 4);
        ts += __shfl_xor(ts, 8);
        lrun[m][r] = lrun[m][r] * alpha + ts;
#pragma unroll
        for (int n = 0; n < 4; ++n) of[m][n][r] *= alpha;
      }
    // P -> LDS (D-layout -> A-layout fix-up)
#pragma unroll
    for (int m = 0; m < 2; ++m)
#pragma unroll
      for (int n = 0; n < 8; ++n)
#pragma unroll
        for (int r = 0; r < 4; ++r)
          P[w][m * 16 + lg * 4 + r][n * 16 + lr] = f2bf(sf[m][n][r]);
    // O += P V
#pragma unroll
    for (int kk = 0; kk < 4; ++kk) {
      short8 pa0 = *(const short8*)&P[w][lr][kk * 32 + lg * 8];
      short8 pa1 = *(const short8*)&P[w][16 + lr][kk * 32 + lg * 8];
#pragma unroll
      for (int n = 0; n < 4; ++n) {
        short8 vf = *(const short8*)&Vb[(size_t)(n * 16 + lr) * S_ + kt + kk * 32 + lg * 8];
        of[0][n] = __builtin_amdgcn_mfma_f32_16x16x32_bf16(pa0, vf, of[0][n], 0, 0, 0);
        of[1][n] = __builtin_amdgcn_mfma_f32_16x16x32_bf16(pa1, vf, of[1][n], 0, 0, 0);
      }
    }
  }
  // finalize + store attn bf16 as [b, s, h*64+hd] == [B*S][1024] row-major
  const int b = bh >> 4, h = bh & 15;
#pragma unroll
  for (int m = 0; m < 2; ++m)
#pragma unroll
    for (int r = 0; r < 4; ++r) {
      float inv = 1.0f / lrun[m][r];
      int row = q0 + m * 16 + lg * 4 + r;
#pragma unroll
      for (int n = 0; n < 4; ++n)
        attn[((size_t)b * S_ + row) * D_ + h * 64 + n * 16 + lr] = f2bf(of[m][n][r] * inv);
    }
}

extern "C" void kernel_launch(void* const* d_in, const int* in_sizes, int n_in,
                              void* d_out, int out_size, void* d_ws, size_t ws_size,
                              hipStream_t stream) {
  const float* x     = (const float*)d_in[0];
  const float* w_qkv = (const float*)d_in[1];
  const float* w_out = (const float*)d_in[2];
  const float* b_out = (const float*)d_in[3];
  float* out = (float*)d_out;

  char* p = (char*)d_ws;
  unsigned short* xb    = (unsigned short*)p; p += (size_t)4096 * 1024 * 2;        // 8 MiB
  unsigned short* wqkvT = (unsigned short*)p; p += (size_t)3072 * 1024 * 2;        // 6 MiB
  unsigned short* woutT = (unsigned short*)p; p += (size_t)1024 * 1024 * 2;        // 2 MiB
  unsigned short* qws   = (unsigned short*)p; p += (size_t)B_ * H_ * S_ * HD_ * 2; // 8 MiB
  unsigned short* kws   = (unsigned short*)p; p += (size_t)B_ * H_ * S_ * HD_ * 2; // 8 MiB
  unsigned short* vTws  = (unsigned short*)p; p += (size_t)B_ * H_ * S_ * HD_ * 2; // 8 MiB
  unsigned short* attnb = (unsigned short*)p; p += (size_t)4096 * 1024 * 2;        // 8 MiB

  // 1. casts / transposes
  cast_kernel<<<4096, 256, 0, stream>>>(x, xb, 4096 * 1024);
  dim3 tb(32, 8);
  transpose_cast_kernel<<<dim3(96, 32), tb, 0, stream>>>(w_qkv, wqkvT, 1024, 3072);
  transpose_cast_kernel<<<dim3(32, 32), tb, 0, stream>>>(w_out, woutT, 1024, 1024);

  // 2. QKV projection
  gemm_bf16<0><<<dim3(24, 32), 256, 0, stream>>>(xb, wqkvT, 1024,
                                                 qws, kws, vTws, nullptr, nullptr);
  // 3. attention
  attn_kernel<<<512, 256, 0, stream>>>(qws, kws, vTws, attnb);

  // 4. output projection + bias
  gemm_bf16<1><<<dim3(8, 32), 256, 0, stream>>>(attnb, woutT, 1024,
                                                nullptr, nullptr, nullptr, out, b_out);
}

// Round 2
// 214.818 us; speedup vs baseline: 1.7391x; 1.7391x over previous
//
#include <hip/hip_runtime.h>
#include <stdint.h>

#define B_  2
#define S_  2048
#define D_  1024
#define H_  16
#define HD_ 64
#define KVT 64
#define NT  (S_ / KVT)   // 32 kv tiles

typedef __attribute__((ext_vector_type(8))) short short8;
typedef __attribute__((ext_vector_type(4))) float f32x4;

__device__ inline unsigned short f2bf(float f) {
  union { float f; unsigned int i; } u; u.f = f;
  unsigned int r = u.i + 0x7FFFu + ((u.i >> 16) & 1u);   // RNE
  return (unsigned short)(r >> 16);
}

__device__ inline void gload16(const void* g, void* l) {
  __builtin_amdgcn_global_load_lds(
      (const __attribute__((address_space(1))) void*)g,
      (__attribute__((address_space(3))) void*)l,
      16, 0, 0);
}

// ---------------- cast x (f32 -> bf16), vectorized x4 ----------------
__global__ void cast_kernel(const float* __restrict__ in,
                            unsigned short* __restrict__ out, int n) {
  int i = (blockIdx.x * blockDim.x + threadIdx.x) * 4;
  if (i >= n) return;
  float4 v = *(const float4*)(in + i);
  union { unsigned short s[4]; uint2 v; } o;
  o.s[0] = f2bf(v.x); o.s[1] = f2bf(v.y); o.s[2] = f2bf(v.z); o.s[3] = f2bf(v.w);
  *(uint2*)(out + i) = o.v;
}

// ---------------- transpose + cast: in[R][C] f32 -> out[C][R] bf16 ----------------
__global__ void transpose_cast_kernel(const float* __restrict__ in,
                                      unsigned short* __restrict__ out,
                                      int R, int C) {
  __shared__ float tile[32][33];
  int bx = blockIdx.x, by = blockIdx.y;
  int tx = threadIdx.x, ty = threadIdx.y;   // block (32,8)
#pragma unroll
  for (int i = 0; i < 4; ++i)
    tile[ty + i * 8][tx] = in[(size_t)(by * 32 + ty + i * 8) * C + bx * 32 + tx];
  __syncthreads();
#pragma unroll
  for (int i = 0; i < 4; ++i)
    out[(size_t)(bx * 32 + ty + i * 8) * R + by * 32 + tx] = f2bf(tile[tx][ty + i * 8]);
}

// ---------------- bf16 GEMM, 128x128 tile, BK=32, m97 structure ----------------
// A[M][K] row-major bf16, Bt[N][K] row-major bf16 (i.e. B transposed).
// MODE 0: QKV epilogue -> q[b,h,s,hd], k[b,h,s,hd], vT[b,h,hd,s], all bf16
// MODE 1: out[i][j] = acc + bias[j], fp32
template <int MODE>
__global__ __launch_bounds__(256)
void gemm_bf16(const unsigned short* __restrict__ A,
               const unsigned short* __restrict__ Bt,
               int K,
               unsigned short* __restrict__ qw,
               unsigned short* __restrict__ kw,
               unsigned short* __restrict__ vTw,
               float* __restrict__ out,
               const float* __restrict__ bias) {
  __shared__ __align__(16) unsigned short As[128 * 32];
  __shared__ __align__(16) unsigned short Bs[128 * 32];
  const int t  = threadIdx.x;
  const int w  = t >> 6, l = t & 63;
  const int lr = l & 15, lg = l >> 4;
  const int wr = w >> 1, wc = w & 1;
  const int bn = blockIdx.x, bm = blockIdx.y;
  const int trow = t >> 2, tcol = (t & 3) << 3;

  const unsigned short* Ab = A  + (size_t)(bm * 128 + trow) * K + tcol;
  const unsigned short* Bb = Bt + (size_t)(bn * 128 + trow) * K + tcol;

  f32x4 acc[4][4];
#pragma unroll
  for (int m = 0; m < 4; ++m)
#pragma unroll
    for (int n = 0; n < 4; ++n)
      acc[m][n] = (f32x4){0.f, 0.f, 0.f, 0.f};

  for (int kt = 0; kt < K; kt += 32) {
    gload16(Ab + kt,          &As[(size_t)t * 8]);
    gload16(Ab + 64 * K + kt, &As[(size_t)(256 + t) * 8]);
    gload16(Bb + kt,          &Bs[(size_t)t * 8]);
    gload16(Bb + 64 * K + kt, &Bs[(size_t)(256 + t) * 8]);
    __syncthreads();
    short8 af[4], bf[4];
#pragma unroll
    for (int m = 0; m < 4; ++m)
      af[m] = *(const short8*)&As[(wr * 64 + m * 16 + lr) * 32 + lg * 8];
#pragma unroll
    for (int n = 0; n < 4; ++n)
      bf[n] = *(const short8*)&Bs[(wc * 64 + n * 16 + lr) * 32 + lg * 8];
#pragma unroll
    for (int m = 0; m < 4; ++m)
#pragma unroll
      for (int n = 0; n < 4; ++n)
        acc[m][n] = __builtin_amdgcn_mfma_f32_16x16x32_bf16(af[m], bf[n], acc[m][n], 0, 0, 0);
    __syncthreads();
  }

#pragma unroll
  for (int m = 0; m < 4; ++m)
#pragma unroll
    for (int n = 0; n < 4; ++n)
#pragma unroll
      for (int r = 0; r < 4; ++r) {
        float v = acc[m][n][r];
        int i = bm * 128 + wr * 64 + m * 16 + lg * 4 + r;
        int j = bn * 128 + wc * 64 + n * 16 + lr;
        if (MODE == 0) {
          unsigned short bv = f2bf(v);
          int b = i >> 11, s = i & 2047;
          int part = j >> 10, rem = j & 1023, h = rem >> 6, hd = rem & 63;
          size_t bh = (size_t)(b * H_ + h);
          if (part == 0)      qw[(bh * S_ + s) * HD_ + hd] = bv;
          else if (part == 1) kw[(bh * S_ + s) * HD_ + hd] = bv;
          else                vTw[(bh * HD_ + hd) * S_ + s] = bv;
        } else {
          out[(size_t)i * D_ + j] = v + bias[j];
        }
      }
}

// ---------------- flash attention: 128 q-rows/block, 4 waves x 32 rows ----------------
// K/V tiles staged in LDS (double-buffered, XOR-swizzled), shared by all 4 waves.
__global__ __launch_bounds__(256)
void attn_kernel(const unsigned short* __restrict__ qw,
                 const unsigned short* __restrict__ kw,
                 const unsigned short* __restrict__ vTw,
                 unsigned short* __restrict__ attn) {
  // Ks/Vs rows are 64 shorts (128 B); data stored with col-XOR swizzle:
  //   lds[row][col ^ ((row&7)*8)]  (units: shorts, 8-short = 16B granules)
  __shared__ __align__(16) unsigned short Ks[2][KVT * 64];
  __shared__ __align__(16) unsigned short Vs[2][KVT * 64];
  __shared__ __align__(16) unsigned short P[4][32][72];   // per-wave P tile

  const int t  = threadIdx.x;
  const int w  = t >> 6, l = t & 63;
  const int lr = l & 15, lg = l >> 4;
  const int blk = blockIdx.x;
  const int bh = blk >> 4, qt = blk & 15;
  const int q0 = qt * 128 + w * 32;
  const unsigned short* Qb = qw  + (size_t)bh * S_ * HD_;
  const unsigned short* Kb = kw  + (size_t)bh * S_ * HD_;
  const unsigned short* Vb = vTw + (size_t)bh * HD_ * S_;

  // staging geometry: thread t covers 16B granule t of each 4KB half-tile.
  const int srow = t >> 3;                       // 0..31 within half-tile
  const int scol = 8 * ((t & 7) ^ (srow & 7));   // pre-swizzled source col (shorts)

  // Q fragments held in registers for the whole kernel
  short8 qf[2][2];
#pragma unroll
  for (int m = 0; m < 2; ++m)
#pragma unroll
    for (int ks = 0; ks < 2; ++ks)
      qf[m][ks] = *(const short8*)&Qb[(size_t)(q0 + m * 16 + lr) * HD_ + ks * 32 + lg * 8];

  f32x4 of[2][4];
  float mrun[2][4], lrun[2][4];
#pragma unroll
  for (int m = 0; m < 2; ++m) {
#pragma unroll
    for (int n = 0; n < 4; ++n) of[m][n] = (f32x4){0.f, 0.f, 0.f, 0.f};
#pragma unroll
    for (int r = 0; r < 4; ++r) { mrun[m][r] = -1e30f; lrun[m][r] = 0.f; }
  }

  // prologue: stage tile 0 into buffer 0
  {
    const int kt = 0;
#pragma unroll
    for (int i = 0; i < 2; ++i) {
      int row = i * 32 + srow;
      gload16(Kb + (size_t)(kt + row) * HD_ + scol, &Ks[0][i * 2048 + t * 8]);
      gload16(Vb + (size_t)row * S_ + kt + scol,    &Vs[0][i * 2048 + t * 8]);
    }
  }
  __syncthreads();

  int cur = 0;
  for (int tt = 0; tt < NT; ++tt) {
    // prefetch next tile into the other buffer (in flight across compute)
    if (tt + 1 < NT) {
      const int kt = (tt + 1) * KVT;
#pragma unroll
      for (int i = 0; i < 2; ++i) {
        int row = i * 32 + srow;
        gload16(Kb + (size_t)(kt + row) * HD_ + scol, &Ks[cur ^ 1][i * 2048 + t * 8]);
        gload16(Vb + (size_t)row * S_ + kt + scol,    &Vs[cur ^ 1][i * 2048 + t * 8]);
      }
    }
    const int kt = tt * KVT;

    // ---- S = Q K^T from LDS (swizzled reads) ----
    f32x4 sf[2][4];
#pragma unroll
    for (int m = 0; m < 2; ++m)
#pragma unroll
      for (int n = 0; n < 4; ++n) sf[m][n] = (f32x4){0.f, 0.f, 0.f, 0.f};
#pragma unroll
    for (int ks = 0; ks < 2; ++ks) {
#pragma unroll
      for (int n = 0; n < 4; ++n) {
        int row = n * 16 + lr;
        short8 kf = *(const short8*)&Ks[cur][row * 64 + ((ks * 32 + lg * 8) ^ ((row & 7) * 8))];
        sf[0][n] = __builtin_amdgcn_mfma_f32_16x16x32_bf16(qf[0][ks], kf, sf[0][n], 0, 0, 0);
        sf[1][n] = __builtin_amdgcn_mfma_f32_16x16x32_bf16(qf[1][ks], kf, sf[1][n], 0, 0, 0);
      }
    }

    // ---- online softmax (rows live in (lg,r); 16 cols per frag in lr lanes) ----
#pragma unroll
    for (int m = 0; m < 2; ++m)
#pragma unroll
      for (int r = 0; r < 4; ++r) {
        float mx = -1e30f;
#pragma unroll
        for (int n = 0; n < 4; ++n) {
          sf[m][n][r] *= 0.125f;                 // 1/sqrt(64)
          mx = fmaxf(mx, sf[m][n][r]);
        }
        mx = fmaxf(mx, __shfl_xor(mx, 1));
        mx = fmaxf(mx, __shfl_xor(mx, 2));
        mx = fmaxf(mx, __shfl_xor(mx, 4));
        mx = fmaxf(mx, __shfl_xor(mx, 8));
        float mo = mrun[m][r];
        float mn = fmaxf(mo, mx);
        mrun[m][r] = mn;
        float alpha = __expf(mo - mn);
        float ts = 0.f;
#pragma unroll
        for (int n = 0; n < 4; ++n) {
          float p = __expf(sf[m][n][r] - mn);
          sf[m][n][r] = p;
          ts += p;
        }
        ts += __shfl_xor(ts, 1);
        ts += __shfl_xor(ts, 2);
        ts += __shfl_xor(ts, 4);
        ts += __shfl_xor(ts, 8);
        lrun[m][r] = lrun[m][r] * alpha + ts;
#pragma unroll
        for (int n = 0; n < 4; ++n) of[m][n][r] *= alpha;
      }

    // ---- P -> LDS (D-layout -> A-layout fix-up), per-wave buffer ----
#pragma unroll
    for (int m = 0; m < 2; ++m)
#pragma unroll
      for (int n = 0; n < 4; ++n)
#pragma unroll
        for (int r = 0; r < 4; ++r)
          P[w][m * 16 + lg * 4 + r][n * 16 + lr] = f2bf(sf[m][n][r]);

    // ---- O += P V (V^T fragments from LDS, swizzled) ----
#pragma unroll
    for (int kk = 0; kk < 2; ++kk) {
      short8 pa0 = *(const short8*)&P[w][lr][kk * 32 + lg * 8];
      short8 pa1 = *(const short8*)&P[w][16 + lr][kk * 32 + lg * 8];
#pragma unroll
      for (int n = 0; n < 4; ++n) {
        int row = n * 16 + lr;
        short8 vf = *(const short8*)&Vs[cur][row * 64 + ((kk * 32 + lg * 8) ^ ((row & 7) * 8))];
        of[0][n] = __builtin_amdgcn_mfma_f32_16x16x32_bf16(pa0, vf, of[0][n], 0, 0, 0);
        of[1][n] = __builtin_amdgcn_mfma_f32_16x16x32_bf16(pa1, vf, of[1][n], 0, 0, 0);
      }
    }

    __syncthreads();   // drains vmcnt (prefetch landed) + lgkm, barrier; swap
    cur ^= 1;
  }

  // finalize + store attn bf16 as [b, s, h*64+hd] == [B*S][1024] row-major
  const int b = bh >> 4, h = bh & 15;
#pragma unroll
  for (int m = 0; m < 2; ++m)
#pragma unroll
    for (int r = 0; r < 4; ++r) {
      float inv = 1.0f / lrun[m][r];
      int row = q0 + m * 16 + lg * 4 + r;
#pragma unroll
      for (int n = 0; n < 4; ++n)
        attn[((size_t)b * S_ + row) * D_ + h * 64 + n * 16 + lr] = f2bf(of[m][n][r] * inv);
    }
}

extern "C" void kernel_launch(void* const* d_in, const int* in_sizes, int n_in,
                              void* d_out, int out_size, void* d_ws, size_t ws_size,
                              hipStream_t stream) {
  const float* x     = (const float*)d_in[0];
  const float* w_qkv = (const float*)d_in[1];
  const float* w_out = (const float*)d_in[2];
  const float* b_out = (const float*)d_in[3];
  float* out = (float*)d_out;

  char* p = (char*)d_ws;
  unsigned short* xb    = (unsigned short*)p; p += (size_t)4096 * 1024 * 2;        // 8 MiB
  unsigned short* wqkvT = (unsigned short*)p; p += (size_t)3072 * 1024 * 2;        // 6 MiB
  unsigned short* woutT = (unsigned short*)p; p += (size_t)1024 * 1024 * 2;        // 2 MiB
  unsigned short* qws   = (unsigned short*)p; p += (size_t)B_ * H_ * S_ * HD_ * 2; // 8 MiB
  unsigned short* kws   = (unsigned short*)p; p += (size_t)B_ * H_ * S_ * HD_ * 2; // 8 MiB
  unsigned short* vTws  = (unsigned short*)p; p += (size_t)B_ * H_ * S_ * HD_ * 2; // 8 MiB
  unsigned short* attnb = (unsigned short*)p; p += (size_t)4096 * 1024 * 2;        // 8 MiB

  // 1. casts / transposes
  cast_kernel<<<4096, 256, 0, stream>>>(x, xb, 4096 * 1024);
  dim3 tb(32, 8);
  transpose_cast_kernel<<<dim3(96, 32), tb, 0, stream>>>(w_qkv, wqkvT, 1024, 3072);
  transpose_cast_kernel<<<dim3(32, 32), tb, 0, stream>>>(w_out, woutT, 1024, 1024);

  // 2. QKV projection
  gemm_bf16<0><<<dim3(24, 32), 256, 0, stream>>>(xb, wqkvT, 1024,
                                                 qws, kws, vTws, nullptr, nullptr);
  // 3. attention
  attn_kernel<<<512, 256, 0, stream>>>(qws, kws, vTws, attnb);

  // 4. output projection + bias
  gemm_bf16<1><<<dim3(8, 32), 256, 0, stream>>>(attnb, woutT, 1024,
                                                nullptr, nullptr, nullptr, out, b_out);
}

// Round 3
// 155.805 us; speedup vs baseline: 2.3979x; 1.3788x over previous
//
#include <hip/hip_runtime.h>
#include <stdint.h>

#define B_  2
#define S_  2048
#define D_  1024
#define H_  16
#define HD_ 64
#define KVT 64
#define NT  (S_ / KVT)   // 32 kv tiles

typedef __attribute__((ext_vector_type(8))) short short8;
typedef __attribute__((ext_vector_type(4))) float f32x4;

__device__ inline unsigned short f2bf(float f) {
  union { float f; unsigned int i; } u; u.f = f;
  unsigned int r = u.i + 0x7FFFu + ((u.i >> 16) & 1u);   // RNE
  return (unsigned short)(r >> 16);
}

__device__ inline uint32_t cvtpk_bf16(float lo, float hi) {
  uint32_t r;
  asm("v_cvt_pk_bf16_f32 %0, %1, %2" : "=v"(r) : "v"(lo), "v"(hi));
  return r;
}

__device__ inline void gload16(const void* g, void* l) {
  __builtin_amdgcn_global_load_lds(
      (const __attribute__((address_space(1))) void*)g,
      (__attribute__((address_space(3))) void*)l,
      16, 0, 0);
}

// ---------------- cast x (f32 -> bf16), vectorized x4 ----------------
__global__ void cast_kernel(const float* __restrict__ in,
                            unsigned short* __restrict__ out, int n) {
  int i = (blockIdx.x * blockDim.x + threadIdx.x) * 4;
  if (i >= n) return;
  float4 v = *(const float4*)(in + i);
  union { unsigned short s[4]; uint2 v; } o;
  o.s[0] = f2bf(v.x); o.s[1] = f2bf(v.y); o.s[2] = f2bf(v.z); o.s[3] = f2bf(v.w);
  *(uint2*)(out + i) = o.v;
}

// ---------------- transpose + cast: in[R][C] f32 -> out[C][R] bf16 ----------------
__global__ void transpose_cast_kernel(const float* __restrict__ in,
                                      unsigned short* __restrict__ out,
                                      int R, int C) {
  __shared__ float tile[32][33];
  int bx = blockIdx.x, by = blockIdx.y;
  int tx = threadIdx.x, ty = threadIdx.y;   // block (32,8)
#pragma unroll
  for (int i = 0; i < 4; ++i)
    tile[ty + i * 8][tx] = in[(size_t)(by * 32 + ty + i * 8) * C + bx * 32 + tx];
  __syncthreads();
#pragma unroll
  for (int i = 0; i < 4; ++i)
    out[(size_t)(bx * 32 + ty + i * 8) * R + by * 32 + tx] = f2bf(tile[tx][ty + i * 8]);
}

// ---------------- bf16 GEMM, 128x128 tile, BK=32, m97 structure ----------------
// MODE 0: QKV epilogue -> q (pre-scaled by 0.125), k, vT (pi-permuted cols)
// MODE 1: out[i][j] = acc + bias[j], fp32
template <int MODE>
__global__ __launch_bounds__(256)
void gemm_bf16(const unsigned short* __restrict__ A,
               const unsigned short* __restrict__ Bt,
               int K,
               unsigned short* __restrict__ qw,
               unsigned short* __restrict__ kw,
               unsigned short* __restrict__ vTw,
               float* __restrict__ out,
               const float* __restrict__ bias) {
  __shared__ __align__(16) unsigned short As[128 * 32];
  __shared__ __align__(16) unsigned short Bs[128 * 32];
  const int t  = threadIdx.x;
  const int w  = t >> 6, l = t & 63;
  const int lr = l & 15, lg = l >> 4;
  const int wr = w >> 1, wc = w & 1;
  const int bn = blockIdx.x, bm = blockIdx.y;
  const int trow = t >> 2, tcol = (t & 3) << 3;

  const unsigned short* Ab = A  + (size_t)(bm * 128 + trow) * K + tcol;
  const unsigned short* Bb = Bt + (size_t)(bn * 128 + trow) * K + tcol;

  f32x4 acc[4][4];
#pragma unroll
  for (int m = 0; m < 4; ++m)
#pragma unroll
    for (int n = 0; n < 4; ++n)
      acc[m][n] = (f32x4){0.f, 0.f, 0.f, 0.f};

  for (int kt = 0; kt < K; kt += 32) {
    gload16(Ab + kt,          &As[(size_t)t * 8]);
    gload16(Ab + 64 * K + kt, &As[(size_t)(256 + t) * 8]);
    gload16(Bb + kt,          &Bs[(size_t)t * 8]);
    gload16(Bb + 64 * K + kt, &Bs[(size_t)(256 + t) * 8]);
    __syncthreads();
    short8 af[4], bf[4];
#pragma unroll
    for (int m = 0; m < 4; ++m)
      af[m] = *(const short8*)&As[(wr * 64 + m * 16 + lr) * 32 + lg * 8];
#pragma unroll
    for (int n = 0; n < 4; ++n)
      bf[n] = *(const short8*)&Bs[(wc * 64 + n * 16 + lr) * 32 + lg * 8];
#pragma unroll
    for (int m = 0; m < 4; ++m)
#pragma unroll
      for (int n = 0; n < 4; ++n)
        acc[m][n] = __builtin_amdgcn_mfma_f32_16x16x32_bf16(af[m], bf[n], acc[m][n], 0, 0, 0);
    __syncthreads();
  }

#pragma unroll
  for (int m = 0; m < 4; ++m)
#pragma unroll
    for (int n = 0; n < 4; ++n)
#pragma unroll
      for (int r = 0; r < 4; ++r) {
        float v = acc[m][n][r];
        int i = bm * 128 + wr * 64 + m * 16 + lg * 4 + r;
        int j = bn * 128 + wc * 64 + n * 16 + lr;
        if (MODE == 0) {
          int b = i >> 11, s = i & 2047;
          int part = j >> 10, rem = j & 1023, h = rem >> 6, hd = rem & 63;
          size_t bh = (size_t)(b * H_ + h);
          if (part == 0) {
            qw[(bh * S_ + s) * HD_ + hd] = f2bf(v * 0.125f);   // fold 1/sqrt(64)
          } else if (part == 1) {
            kw[(bh * S_ + s) * HD_ + hd] = f2bf(v);
          } else {
            // store V^T with pi-permuted column order within each 64-tile:
            // pi_inv(K) = (K&32) | ((K>>2)&3)<<3 | ((K>>4)&1)<<2 | (K&3)
            int s6 = s & 63;
            int sp = (s & ~63) | (s6 & 32) | (((s6 >> 2) & 3) << 3)
                   | (((s6 >> 4) & 1) << 2) | (s6 & 3);
            vTw[(bh * HD_ + hd) * S_ + sp] = f2bf(v);
          }
        } else {
          out[(size_t)i * D_ + j] = v + bias[j];
        }
      }
}

// ---------------- flash attention: swapped QK^T, zero-shuffle PV ----------------
// 128 q-rows/block, 4 waves x 32 rows. K/V staged in LDS (dbuf, XOR-swizzled).
// S^T = mfma(K, Q): lane owns q-col (lr), 16 k-values in-lane -> softmax with
// 2 shfls. V columns pre-permuted (pi) so PV's B-frag == packed P registers.
__global__ __launch_bounds__(256)
void attn_kernel(const unsigned short* __restrict__ qw,
                 const unsigned short* __restrict__ kw,
                 const unsigned short* __restrict__ vTw,
                 unsigned short* __restrict__ attn) {
  __shared__ __align__(16) unsigned short Ks[2][KVT * 64];
  __shared__ __align__(16) unsigned short Vs[2][KVT * 64];

  const int t  = threadIdx.x;
  const int w  = t >> 6, l = t & 63;
  const int lr = l & 15, lg = l >> 4;
  const int blk = blockIdx.x;
  const int bh = blk >> 4, qt = blk & 15;
  const int q0 = qt * 128 + w * 32;
  const unsigned short* Qb = qw  + (size_t)bh * S_ * HD_;
  const unsigned short* Kb = kw  + (size_t)bh * S_ * HD_;
  const unsigned short* Vb = vTw + (size_t)bh * HD_ * S_;

  // staging geometry: thread t covers 16B granule t of each 4KB half-tile.
  const int srow = t >> 3;                       // 0..31 within half-tile
  const int scol = 8 * ((t & 7) ^ (srow & 7));   // pre-swizzled source col (shorts)

  // Q fragments (B-operand layout == same addressing as before), held in regs
  short8 qf[2][2];
#pragma unroll
  for (int m = 0; m < 2; ++m)
#pragma unroll
    for (int ks = 0; ks < 2; ++ks)
      qf[m][ks] = *(const short8*)&Qb[(size_t)(q0 + m * 16 + lr) * HD_ + ks * 32 + lg * 8];

  f32x4 of[2][4];               // O^T[d][q]: q=lr, d = nd*16+lg*4+r
  float mrun[2], lrun[2];       // per-lane: row max (full), row sum (partial)
#pragma unroll
  for (int m = 0; m < 2; ++m) {
#pragma unroll
    for (int n = 0; n < 4; ++n) of[m][n] = (f32x4){0.f, 0.f, 0.f, 0.f};
    mrun[m] = -1e30f; lrun[m] = 0.f;
  }

  // prologue: stage tile 0 into buffer 0
#pragma unroll
  for (int i = 0; i < 2; ++i) {
    int row = i * 32 + srow;
    gload16(Kb + (size_t)row * HD_ + scol,   &Ks[0][i * 2048 + t * 8]);
    gload16(Vb + (size_t)row * S_ + scol,    &Vs[0][i * 2048 + t * 8]);
  }
  __syncthreads();

  int cur = 0;
  for (int tt = 0; tt < NT; ++tt) {
    if (tt + 1 < NT) {
      const int kt = (tt + 1) * KVT;
#pragma unroll
      for (int i = 0; i < 2; ++i) {
        int row = i * 32 + srow;
        gload16(Kb + (size_t)(kt + row) * HD_ + scol, &Ks[cur ^ 1][i * 2048 + t * 8]);
        gload16(Vb + (size_t)row * S_ + kt + scol,    &Vs[cur ^ 1][i * 2048 + t * 8]);
      }
    }

    // ---- S^T = mfma(K, Q): sfT[m][n] = S^T[k = n*16+lg*4+r][q = q0+m*16+lr] ----
    f32x4 sfT[2][4];
#pragma unroll
    for (int m = 0; m < 2; ++m)
#pragma unroll
      for (int n = 0; n < 4; ++n) sfT[m][n] = (f32x4){0.f, 0.f, 0.f, 0.f};
#pragma unroll
    for (int ks = 0; ks < 2; ++ks) {
#pragma unroll
      for (int n = 0; n < 4; ++n) {
        int row = n * 16 + lr;
        short8 kf = *(const short8*)&Ks[cur][row * 64 + ((ks * 32 + lg * 8) ^ ((row & 7) * 8))];
        sfT[0][n] = __builtin_amdgcn_mfma_f32_16x16x32_bf16(kf, qf[0][ks], sfT[0][n], 0, 0, 0);
        sfT[1][n] = __builtin_amdgcn_mfma_f32_16x16x32_bf16(kf, qf[1][ks], sfT[1][n], 0, 0, 0);
      }
    }

    // ---- softmax: 16 k-values in-lane, reduce across lg with 2 shfls ----
    uint32_t pk[2][4][2];
#pragma unroll
    for (int m = 0; m < 2; ++m) {
      float mx = sfT[m][0][0];
#pragma unroll
      for (int n = 0; n < 4; ++n)
#pragma unroll
        for (int r = 0; r < 4; ++r) mx = fmaxf(mx, sfT[m][n][r]);
      mx = fmaxf(mx, __shfl_xor(mx, 16));
      mx = fmaxf(mx, __shfl_xor(mx, 32));
      float mo = mrun[m];
      float mn = fmaxf(mo, mx);
      mrun[m] = mn;
      float alpha = __expf(mo - mn);
      float ts = 0.f;
#pragma unroll
      for (int n = 0; n < 4; ++n)
#pragma unroll
        for (int r = 0; r < 4; ++r) {
          float p = __expf(sfT[m][n][r] - mn);
          sfT[m][n][r] = p;
          ts += p;
        }
      lrun[m] = lrun[m] * alpha + ts;        // per-lane partial sum
#pragma unroll
      for (int n = 0; n < 4; ++n) {
        pk[m][n][0] = cvtpk_bf16(sfT[m][n][0], sfT[m][n][1]);
        pk[m][n][1] = cvtpk_bf16(sfT[m][n][2], sfT[m][n][3]);
      }
#pragma unroll
      for (int n = 0; n < 4; ++n)
#pragma unroll
        for (int r = 0; r < 4; ++r) of[m][n][r] *= alpha;
    }

    // ---- O^T += V^T P^T : B-frag is lane-local packed P (pi-permuted V) ----
    union { uint32_t u[4]; short8 v; } pb[2][2];
#pragma unroll
    for (int m = 0; m < 2; ++m)
#pragma unroll
      for (int kk = 0; kk < 2; ++kk) {
        pb[m][kk].u[0] = pk[m][2 * kk][0];
        pb[m][kk].u[1] = pk[m][2 * kk][1];
        pb[m][kk].u[2] = pk[m][2 * kk + 1][0];
        pb[m][kk].u[3] = pk[m][2 * kk + 1][1];
      }
#pragma unroll
    for (int nd = 0; nd < 4; ++nd)
#pragma unroll
      for (int kk = 0; kk < 2; ++kk) {
        int row = nd * 16 + lr;
        short8 vf = *(const short8*)&Vs[cur][row * 64 + ((kk * 32 + lg * 8) ^ ((row & 7) * 8))];
        of[0][nd] = __builtin_amdgcn_mfma_f32_16x16x32_bf16(vf, pb[0][kk].v, of[0][nd], 0, 0, 0);
        of[1][nd] = __builtin_amdgcn_mfma_f32_16x16x32_bf16(vf, pb[1][kk].v, of[1][nd], 0, 0, 0);
      }

    __syncthreads();   // drains vmcnt (prefetch landed), barrier; swap
    cur ^= 1;
  }

  // finalize: reduce partial row-sums across lg, store O^T
  const int b = bh >> 4, h = bh & 15;
#pragma unroll
  for (int m = 0; m < 2; ++m) {
    float ls = lrun[m];
    ls += __shfl_xor(ls, 16);
    ls += __shfl_xor(ls, 32);
    float inv = 1.0f / ls;
    int q = q0 + m * 16 + lr;
#pragma unroll
    for (int nd = 0; nd < 4; ++nd)
#pragma unroll
      for (int r = 0; r < 4; ++r)
        attn[((size_t)b * S_ + q) * D_ + h * 64 + nd * 16 + lg * 4 + r] =
            f2bf(of[m][nd][r] * inv);
  }
}

extern "C" void kernel_launch(void* const* d_in, const int* in_sizes, int n_in,
                              void* d_out, int out_size, void* d_ws, size_t ws_size,
                              hipStream_t stream) {
  const float* x     = (const float*)d_in[0];
  const float* w_qkv = (const float*)d_in[1];
  const float* w_out = (const float*)d_in[2];
  const float* b_out = (const float*)d_in[3];
  float* out = (float*)d_out;

  char* p = (char*)d_ws;
  unsigned short* xb    = (unsigned short*)p; p += (size_t)4096 * 1024 * 2;        // 8 MiB
  unsigned short* wqkvT = (unsigned short*)p; p += (size_t)3072 * 1024 * 2;        // 6 MiB
  unsigned short* woutT = (unsigned short*)p; p += (size_t)1024 * 1024 * 2;        // 2 MiB
  unsigned short* qws   = (unsigned short*)p; p += (size_t)B_ * H_ * S_ * HD_ * 2; // 8 MiB
  unsigned short* kws   = (unsigned short*)p; p += (size_t)B_ * H_ * S_ * HD_ * 2; // 8 MiB
  unsigned short* vTws  = (unsigned short*)p; p += (size_t)B_ * H_ * S_ * HD_ * 2; // 8 MiB
  unsigned short* attnb = (unsigned short*)p; p += (size_t)4096 * 1024 * 2;        // 8 MiB

  // 1. casts / transposes
  cast_kernel<<<4096, 256, 0, stream>>>(x, xb, 4096 * 1024);
  dim3 tb(32, 8);
  transpose_cast_kernel<<<dim3(96, 32), tb, 0, stream>>>(w_qkv, wqkvT, 1024, 3072);
  transpose_cast_kernel<<<dim3(32, 32), tb, 0, stream>>>(w_out, woutT, 1024, 1024);

  // 2. QKV projection
  gemm_bf16<0><<<dim3(24, 32), 256, 0, stream>>>(xb, wqkvT, 1024,
                                                 qws, kws, vTws, nullptr, nullptr);
  // 3. attention
  attn_kernel<<<512, 256, 0, stream>>>(qws, kws, vTws, attnb);

  // 4. output projection + bias
  gemm_bf16<1><<<dim3(8, 32), 256, 0, stream>>>(attnb, woutT, 1024,
                                                nullptr, nullptr, nullptr, out, b_out);
}

// Round 4
// 147.268 us; speedup vs baseline: 2.5369x; 1.0580x over previous
//
#include <hip/hip_runtime.h>
#include <stdint.h>

#define B_  2
#define S_  2048
#define D_  1024
#define H_  16
#define HD_ 64
#define KVT 64
#define NT  (S_ / KVT)   // 32 kv tiles

typedef __attribute__((ext_vector_type(8))) short short8;
typedef __attribute__((ext_vector_type(4))) float f32x4;

__device__ inline unsigned short f2bf(float f) {
  union { float f; unsigned int i; } u; u.f = f;
  unsigned int r = u.i + 0x7FFFu + ((u.i >> 16) & 1u);   // RNE
  return (unsigned short)(r >> 16);
}

__device__ inline uint32_t cvtpk_bf16(float lo, float hi) {
  uint32_t r;
  asm("v_cvt_pk_bf16_f32 %0, %1, %2" : "=v"(r) : "v"(lo), "v"(hi));
  return r;
}

__device__ inline void gload16(const void* g, void* l) {
  __builtin_amdgcn_global_load_lds(
      (const __attribute__((address_space(1))) void*)g,
      (__attribute__((address_space(3))) void*)l,
      16, 0, 0);
}

// ---------------- cast x (f32 -> bf16), vectorized x4 ----------------
__global__ void cast_kernel(const float* __restrict__ in,
                            unsigned short* __restrict__ out, int n) {
  int i = (blockIdx.x * blockDim.x + threadIdx.x) * 4;
  if (i >= n) return;
  float4 v = *(const float4*)(in + i);
  union { unsigned short s[4]; uint2 v; } o;
  o.s[0] = f2bf(v.x); o.s[1] = f2bf(v.y); o.s[2] = f2bf(v.z); o.s[3] = f2bf(v.w);
  *(uint2*)(out + i) = o.v;
}

// ---------------- transpose + cast: in[R][C] f32 -> out[C][R] bf16 ----------------
__global__ void transpose_cast_kernel(const float* __restrict__ in,
                                      unsigned short* __restrict__ out,
                                      int R, int C) {
  __shared__ float tile[32][33];
  int bx = blockIdx.x, by = blockIdx.y;
  int tx = threadIdx.x, ty = threadIdx.y;   // block (32,8)
#pragma unroll
  for (int i = 0; i < 4; ++i)
    tile[ty + i * 8][tx] = in[(size_t)(by * 32 + ty + i * 8) * C + bx * 32 + tx];
  __syncthreads();
#pragma unroll
  for (int i = 0; i < 4; ++i)
    out[(size_t)(bx * 32 + ty + i * 8) * R + by * 32 + tx] = f2bf(tile[tx][ty + i * 8]);
}

// ---------------- QKV GEMM, 128x128 tile, BK=32, m97 structure ----------------
// A[4096][1024] bf16, Bt[3072][1024] bf16. Epilogue:
//   q (pre-scaled by 0.125*log2e for exp2 softmax), k, vT (pi-permuted cols)
__global__ __launch_bounds__(256)
void gemm_qkv(const unsigned short* __restrict__ A,
              const unsigned short* __restrict__ Bt,
              unsigned short* __restrict__ qw,
              unsigned short* __restrict__ kw,
              unsigned short* __restrict__ vTw) {
  const int K = 1024;
  __shared__ __align__(16) unsigned short As[128 * 32];
  __shared__ __align__(16) unsigned short Bs[128 * 32];
  const int t  = threadIdx.x;
  const int w  = t >> 6, l = t & 63;
  const int lr = l & 15, lg = l >> 4;
  const int wr = w >> 1, wc = w & 1;
  const int bn = blockIdx.x, bm = blockIdx.y;
  const int trow = t >> 2, tcol = (t & 3) << 3;

  const unsigned short* Ab = A  + (size_t)(bm * 128 + trow) * K + tcol;
  const unsigned short* Bb = Bt + (size_t)(bn * 128 + trow) * K + tcol;

  f32x4 acc[4][4];
#pragma unroll
  for (int m = 0; m < 4; ++m)
#pragma unroll
    for (int n = 0; n < 4; ++n)
      acc[m][n] = (f32x4){0.f, 0.f, 0.f, 0.f};

  for (int kt = 0; kt < K; kt += 32) {
    gload16(Ab + kt,          &As[(size_t)t * 8]);
    gload16(Ab + 64 * K + kt, &As[(size_t)(256 + t) * 8]);
    gload16(Bb + kt,          &Bs[(size_t)t * 8]);
    gload16(Bb + 64 * K + kt, &Bs[(size_t)(256 + t) * 8]);
    __syncthreads();
    short8 af[4], bf[4];
#pragma unroll
    for (int m = 0; m < 4; ++m)
      af[m] = *(const short8*)&As[(wr * 64 + m * 16 + lr) * 32 + lg * 8];
#pragma unroll
    for (int n = 0; n < 4; ++n)
      bf[n] = *(const short8*)&Bs[(wc * 64 + n * 16 + lr) * 32 + lg * 8];
#pragma unroll
    for (int m = 0; m < 4; ++m)
#pragma unroll
      for (int n = 0; n < 4; ++n)
        acc[m][n] = __builtin_amdgcn_mfma_f32_16x16x32_bf16(af[m], bf[n], acc[m][n], 0, 0, 0);
    __syncthreads();
  }

#pragma unroll
  for (int m = 0; m < 4; ++m)
#pragma unroll
    for (int n = 0; n < 4; ++n)
#pragma unroll
      for (int r = 0; r < 4; ++r) {
        float v = acc[m][n][r];
        int i = bm * 128 + wr * 64 + m * 16 + lg * 4 + r;
        int j = bn * 128 + wc * 64 + n * 16 + lr;
        int b = i >> 11, s = i & 2047;
        int part = j >> 10, rem = j & 1023, h = rem >> 6, hd = rem & 63;
        size_t bh = (size_t)(b * H_ + h);
        if (part == 0) {
          // fold (1/sqrt(64)) * log2(e) so softmax uses native exp2
          qw[(bh * S_ + s) * HD_ + hd] = f2bf(v * 0.1803368801f);
        } else if (part == 1) {
          kw[(bh * S_ + s) * HD_ + hd] = f2bf(v);
        } else {
          // store V^T with pi-permuted column order within each 64-tile:
          // pi_inv(K) = (K&32) | ((K>>2)&3)<<3 | ((K>>4)&1)<<2 | (K&3)
          int s6 = s & 63;
          int sp = (s & ~63) | (s6 & 32) | (((s6 >> 2) & 3) << 3)
                 | (((s6 >> 4) & 1) << 2) | (s6 & 3);
          vTw[(bh * HD_ + hd) * S_ + sp] = f2bf(v);
        }
      }
}

// ---------------- out projection GEMM, 128x64 tile (2 blocks/CU) ----------------
// A[4096][1024] bf16 (attn), Bt[1024][1024] bf16 (w_out^T). out fp32 + bias.
__global__ __launch_bounds__(256)
void gemm_out(const unsigned short* __restrict__ A,
              const unsigned short* __restrict__ Bt,
              float* __restrict__ out,
              const float* __restrict__ bias) {
  const int K = 1024;
  __shared__ __align__(16) unsigned short As[128 * 32];
  __shared__ __align__(16) unsigned short Bs[64 * 32];
  const int t  = threadIdx.x;
  const int w  = t >> 6, l = t & 63;
  const int lr = l & 15, lg = l >> 4;
  const int wr = w >> 1, wc = w & 1;
  const int bn = blockIdx.x, bm = blockIdx.y;
  const int trow = t >> 2, tcol = (t & 3) << 3;

  const unsigned short* Ab = A  + (size_t)(bm * 128 + trow) * K + tcol;
  const unsigned short* Bb = Bt + (size_t)(bn * 64 + trow) * K + tcol;

  f32x4 acc[4][2];
#pragma unroll
  for (int m = 0; m < 4; ++m)
#pragma unroll
    for (int n = 0; n < 2; ++n)
      acc[m][n] = (f32x4){0.f, 0.f, 0.f, 0.f};

  for (int kt = 0; kt < K; kt += 32) {
    gload16(Ab + kt,          &As[(size_t)t * 8]);
    gload16(Ab + 64 * K + kt, &As[(size_t)(256 + t) * 8]);
    gload16(Bb + kt,          &Bs[(size_t)t * 8]);
    __syncthreads();
    short8 af[4], bf[2];
#pragma unroll
    for (int m = 0; m < 4; ++m)
      af[m] = *(const short8*)&As[(wr * 64 + m * 16 + lr) * 32 + lg * 8];
#pragma unroll
    for (int n = 0; n < 2; ++n)
      bf[n] = *(const short8*)&Bs[(wc * 32 + n * 16 + lr) * 32 + lg * 8];
#pragma unroll
    for (int m = 0; m < 4; ++m)
#pragma unroll
      for (int n = 0; n < 2; ++n)
        acc[m][n] = __builtin_amdgcn_mfma_f32_16x16x32_bf16(af[m], bf[n], acc[m][n], 0, 0, 0);
    __syncthreads();
  }

#pragma unroll
  for (int m = 0; m < 4; ++m)
#pragma unroll
    for (int n = 0; n < 2; ++n)
#pragma unroll
      for (int r = 0; r < 4; ++r) {
        int i = bm * 128 + wr * 64 + m * 16 + lg * 4 + r;
        int j = bn * 64 + wc * 32 + n * 16 + lr;
        out[(size_t)i * D_ + j] = acc[m][n][r] + bias[j];
      }
}

// ---------------- flash attention v4: exp2 + defer-max + MFMA row-sum ----------------
// 128 q-rows/block, 4 waves x 32 rows. K/V staged in LDS (dbuf, XOR-swizzled).
// S^T = mfma(K, Q) (Q pre-scaled by 0.125*log2e). V columns pre-pi-permuted so
// PV's B-frag is the lane-local packed P. Row-sums via mfma(ones, P).
__global__ __launch_bounds__(256)
void attn_kernel(const unsigned short* __restrict__ qw,
                 const unsigned short* __restrict__ kw,
                 const unsigned short* __restrict__ vTw,
                 unsigned short* __restrict__ attn) {
  __shared__ __align__(16) unsigned short Ks[2][KVT * 64];
  __shared__ __align__(16) unsigned short Vs[2][KVT * 64];

  const int t  = threadIdx.x;
  const int w  = t >> 6, l = t & 63;
  const int lr = l & 15, lg = l >> 4;
  const int blk = blockIdx.x;
  const int bh = blk >> 4, qt = blk & 15;
  const int q0 = qt * 128 + w * 32;
  const unsigned short* Qb = qw  + (size_t)bh * S_ * HD_;
  const unsigned short* Kb = kw  + (size_t)bh * S_ * HD_;
  const unsigned short* Vb = vTw + (size_t)bh * HD_ * S_;

  const int srow = t >> 3;                       // 0..31 within half-tile
  const int scol = 8 * ((t & 7) ^ (srow & 7));   // pre-swizzled source col (shorts)

  const short8 ones = {16256, 16256, 16256, 16256, 16256, 16256, 16256, 16256}; // bf16 1.0

  short8 qf[2][2];
#pragma unroll
  for (int m = 0; m < 2; ++m)
#pragma unroll
    for (int ks = 0; ks < 2; ++ks)
      qf[m][ks] = *(const short8*)&Qb[(size_t)(q0 + m * 16 + lr) * HD_ + ks * 32 + lg * 8];

  f32x4 of[2][4];               // O^T[d][q]: q=lr, d = nd*16+lg*4+r
  f32x4 osum[2];                // row-sum accumulator (replicated across regs/lg)
  float mrun[2];
#pragma unroll
  for (int m = 0; m < 2; ++m) {
#pragma unroll
    for (int n = 0; n < 4; ++n) of[m][n] = (f32x4){0.f, 0.f, 0.f, 0.f};
    osum[m] = (f32x4){0.f, 0.f, 0.f, 0.f};
    mrun[m] = -1e30f;
  }

  // prologue: stage tile 0 into buffer 0
#pragma unroll
  for (int i = 0; i < 2; ++i) {
    int row = i * 32 + srow;
    gload16(Kb + (size_t)row * HD_ + scol, &Ks[0][i * 2048 + t * 8]);
    gload16(Vb + (size_t)row * S_ + scol,  &Vs[0][i * 2048 + t * 8]);
  }
  __syncthreads();

  int cur = 0;
  for (int tt = 0; tt < NT; ++tt) {
    if (tt + 1 < NT) {
      const int kt = (tt + 1) * KVT;
#pragma unroll
      for (int i = 0; i < 2; ++i) {
        int row = i * 32 + srow;
        gload16(Kb + (size_t)(kt + row) * HD_ + scol, &Ks[cur ^ 1][i * 2048 + t * 8]);
        gload16(Vb + (size_t)row * S_ + kt + scol,    &Vs[cur ^ 1][i * 2048 + t * 8]);
      }
    }

    // ---- S^T = mfma(K, Q) : sfT[m][n] = S^T[k = n*16+lg*4+r][q = q0+m*16+lr] ----
    f32x4 sfT[2][4];
#pragma unroll
    for (int m = 0; m < 2; ++m)
#pragma unroll
      for (int n = 0; n < 4; ++n) sfT[m][n] = (f32x4){0.f, 0.f, 0.f, 0.f};
    __builtin_amdgcn_s_setprio(1);
#pragma unroll
    for (int ks = 0; ks < 2; ++ks) {
#pragma unroll
      for (int n = 0; n < 4; ++n) {
        int row = n * 16 + lr;
        short8 kf = *(const short8*)&Ks[cur][row * 64 + ((ks * 32 + lg * 8) ^ ((row & 7) * 8))];
        sfT[0][n] = __builtin_amdgcn_mfma_f32_16x16x32_bf16(kf, qf[0][ks], sfT[0][n], 0, 0, 0);
        sfT[1][n] = __builtin_amdgcn_mfma_f32_16x16x32_bf16(kf, qf[1][ks], sfT[1][n], 0, 0, 0);
      }
    }
    __builtin_amdgcn_s_setprio(0);

    // ---- softmax in log2 domain: tile max (tree), defer-max, exp2, pack ----
    float mx[2];
    bool need = false;
#pragma unroll
    for (int m = 0; m < 2; ++m) {
      float c0 = fmaxf(fmaxf(sfT[m][0][0], sfT[m][1][0]), fmaxf(sfT[m][2][0], sfT[m][3][0]));
      float c1 = fmaxf(fmaxf(sfT[m][0][1], sfT[m][1][1]), fmaxf(sfT[m][2][1], sfT[m][3][1]));
      float c2 = fmaxf(fmaxf(sfT[m][0][2], sfT[m][1][2]), fmaxf(sfT[m][2][2], sfT[m][3][2]));
      float c3 = fmaxf(fmaxf(sfT[m][0][3], sfT[m][1][3]), fmaxf(sfT[m][2][3], sfT[m][3][3]));
      float v = fmaxf(fmaxf(c0, c1), fmaxf(c2, c3));
      v = fmaxf(v, __shfl_xor(v, 16));
      v = fmaxf(v, __shfl_xor(v, 32));
      mx[m] = v;
      need = need || (v > mrun[m] + 10.0f);   // THR in log2 units
    }
    if (__any(need)) {
#pragma unroll
      for (int m = 0; m < 2; ++m) {
        float mn = fmaxf(mrun[m], mx[m]);
        float al = exp2f(mrun[m] - mn);
        mrun[m] = mn;
#pragma unroll
        for (int n = 0; n < 4; ++n)
#pragma unroll
          for (int r = 0; r < 4; ++r) of[m][n][r] *= al;
#pragma unroll
        for (int r = 0; r < 4; ++r) osum[m][r] *= al;
      }
    }
    uint32_t pk[2][4][2];
#pragma unroll
    for (int m = 0; m < 2; ++m) {
      float mm = mrun[m];
#pragma unroll
      for (int n = 0; n < 4; ++n) {
        float e0 = exp2f(sfT[m][n][0] - mm);
        float e1 = exp2f(sfT[m][n][1] - mm);
        float e2 = exp2f(sfT[m][n][2] - mm);
        float e3 = exp2f(sfT[m][n][3] - mm);
        pk[m][n][0] = cvtpk_bf16(e0, e1);
        pk[m][n][1] = cvtpk_bf16(e2, e3);
      }
    }

    // ---- O^T += V^T P^T and row-sums += 1 . P^T (all on MFMA pipe) ----
    union { uint32_t u[4]; short8 v; } pb[2][2];
#pragma unroll
    for (int m = 0; m < 2; ++m)
#pragma unroll
      for (int kk = 0; kk < 2; ++kk) {
        pb[m][kk].u[0] = pk[m][2 * kk][0];
        pb[m][kk].u[1] = pk[m][2 * kk][1];
        pb[m][kk].u[2] = pk[m][2 * kk + 1][0];
        pb[m][kk].u[3] = pk[m][2 * kk + 1][1];
      }
    __builtin_amdgcn_s_setprio(1);
#pragma unroll
    for (int nd = 0; nd < 4; ++nd)
#pragma unroll
      for (int kk = 0; kk < 2; ++kk) {
        int row = nd * 16 + lr;
        short8 vf = *(const short8*)&Vs[cur][row * 64 + ((kk * 32 + lg * 8) ^ ((row & 7) * 8))];
        of[0][nd] = __builtin_amdgcn_mfma_f32_16x16x32_bf16(vf, pb[0][kk].v, of[0][nd], 0, 0, 0);
        of[1][nd] = __builtin_amdgcn_mfma_f32_16x16x32_bf16(vf, pb[1][kk].v, of[1][nd], 0, 0, 0);
      }
#pragma unroll
    for (int m = 0; m < 2; ++m)
#pragma unroll
      for (int kk = 0; kk < 2; ++kk)
        osum[m] = __builtin_amdgcn_mfma_f32_16x16x32_bf16(ones, pb[m][kk].v, osum[m], 0, 0, 0);
    __builtin_amdgcn_s_setprio(0);

    __syncthreads();   // drains vmcnt (prefetch landed), barrier; swap
    cur ^= 1;
  }

  // finalize: osum[m][0] holds the full row sum (replicated); store O^T
  const int b = bh >> 4, h = bh & 15;
#pragma unroll
  for (int m = 0; m < 2; ++m) {
    float inv = 1.0f / osum[m][0];
    int q = q0 + m * 16 + lr;
#pragma unroll
    for (int nd = 0; nd < 4; ++nd)
#pragma unroll
      for (int r = 0; r < 4; ++r)
        attn[((size_t)b * S_ + q) * D_ + h * 64 + nd * 16 + lg * 4 + r] =
            f2bf(of[m][nd][r] * inv);
  }
}

extern "C" void kernel_launch(void* const* d_in, const int* in_sizes, int n_in,
                              void* d_out, int out_size, void* d_ws, size_t ws_size,
                              hipStream_t stream) {
  const float* x     = (const float*)d_in[0];
  const float* w_qkv = (const float*)d_in[1];
  const float* w_out = (const float*)d_in[2];
  const float* b_out = (const float*)d_in[3];
  float* out = (float*)d_out;

  char* p = (char*)d_ws;
  unsigned short* xb    = (unsigned short*)p; p += (size_t)4096 * 1024 * 2;        // 8 MiB
  unsigned short* wqkvT = (unsigned short*)p; p += (size_t)3072 * 1024 * 2;        // 6 MiB
  unsigned short* woutT = (unsigned short*)p; p += (size_t)1024 * 1024 * 2;        // 2 MiB
  unsigned short* qws   = (unsigned short*)p; p += (size_t)B_ * H_ * S_ * HD_ * 2; // 8 MiB
  unsigned short* kws   = (unsigned short*)p; p += (size_t)B_ * H_ * S_ * HD_ * 2; // 8 MiB
  unsigned short* vTws  = (unsigned short*)p; p += (size_t)B_ * H_ * S_ * HD_ * 2; // 8 MiB
  unsigned short* attnb = (unsigned short*)p; p += (size_t)4096 * 1024 * 2;        // 8 MiB

  // 1. casts / transposes
  cast_kernel<<<4096, 256, 0, stream>>>(x, xb, 4096 * 1024);
  dim3 tb(32, 8);
  transpose_cast_kernel<<<dim3(96, 32), tb, 0, stream>>>(w_qkv, wqkvT, 1024, 3072);
  transpose_cast_kernel<<<dim3(32, 32), tb, 0, stream>>>(w_out, woutT, 1024, 1024);

  // 2. QKV projection
  gemm_qkv<<<dim3(24, 32), 256, 0, stream>>>(xb, wqkvT, qws, kws, vTws);

  // 3. attention
  attn_kernel<<<512, 256, 0, stream>>>(qws, kws, vTws, attnb);

  // 4. output projection + bias (128x64 tiles -> 512 blocks, 2/CU)
  gemm_out<<<dim3(16, 32), 256, 0, stream>>>(attnb, woutT, out, b_out);
}

// Round 5
// 128.659 us; speedup vs baseline: 2.9038x; 1.1446x over previous
//
#include <hip/hip_runtime.h>
#include <stdint.h>

#define B_  2
#define S_  2048
#define D_  1024
#define H_  16
#define HD_ 64
#define KVT 64
#define NT  (S_ / KVT)   // 32 kv tiles

typedef __attribute__((ext_vector_type(8))) short short8;
typedef __attribute__((ext_vector_type(4))) float f32x4;

__device__ inline unsigned short f2bf(float f) {
  union { float f; unsigned int i; } u; u.f = f;
  unsigned int r = u.i + 0x7FFFu + ((u.i >> 16) & 1u);   // RNE
  return (unsigned short)(r >> 16);
}

__device__ inline uint32_t cvtpk_bf16(float lo, float hi) {
  uint32_t r;
  asm("v_cvt_pk_bf16_f32 %0, %1, %2" : "=v"(r) : "v"(lo), "v"(hi));
  return r;
}

// raw v_exp_f32 (2^x) — libm exp2f is a multi-inst correctly-rounded expansion
__device__ inline float fexp2(float x) {
  float r;
  asm("v_exp_f32 %0, %1" : "=v"(r) : "v"(x));
  return r;
}

__device__ inline void gload16(const void* g, void* l) {
  __builtin_amdgcn_global_load_lds(
      (const __attribute__((address_space(1))) void*)g,
      (__attribute__((address_space(3))) void*)l,
      16, 0, 0);
}

// ---------------- cast x (f32 -> bf16), vectorized x4 ----------------
__global__ void cast_kernel(const float* __restrict__ in,
                            unsigned short* __restrict__ out, int n) {
  int i = (blockIdx.x * blockDim.x + threadIdx.x) * 4;
  if (i >= n) return;
  float4 v = *(const float4*)(in + i);
  union { unsigned short s[4]; uint2 v; } o;
  o.s[0] = f2bf(v.x); o.s[1] = f2bf(v.y); o.s[2] = f2bf(v.z); o.s[3] = f2bf(v.w);
  *(uint2*)(out + i) = o.v;
}

// ---------------- transpose + cast: in[R][C] f32 -> out[C][R] bf16 ----------------
__global__ void transpose_cast_kernel(const float* __restrict__ in,
                                      unsigned short* __restrict__ out,
                                      int R, int C) {
  __shared__ float tile[32][33];
  int bx = blockIdx.x, by = blockIdx.y;
  int tx = threadIdx.x, ty = threadIdx.y;   // block (32,8)
#pragma unroll
  for (int i = 0; i < 4; ++i)
    tile[ty + i * 8][tx] = in[(size_t)(by * 32 + ty + i * 8) * C + bx * 32 + tx];
  __syncthreads();
#pragma unroll
  for (int i = 0; i < 4; ++i)
    out[(size_t)(bx * 32 + ty + i * 8) * R + by * 32 + tx] = f2bf(tile[tx][ty + i * 8]);
}

// ---------------- QKV GEMM, 128x128 tile, BK=64, XOR-swizzled LDS ----------------
// A[4096][1024] bf16, Bt[3072][1024] bf16. Epilogue:
//   q (pre-scaled by 0.125*log2e for exp2 softmax), k, vT (pi-permuted cols)
__global__ __launch_bounds__(256, 3)
void gemm_qkv(const unsigned short* __restrict__ A,
              const unsigned short* __restrict__ Bt,
              unsigned short* __restrict__ qw,
              unsigned short* __restrict__ kw,
              unsigned short* __restrict__ vTw) {
  const int K = 1024;
  __shared__ __align__(16) unsigned short As[128 * 64];
  __shared__ __align__(16) unsigned short Bs[128 * 64];
  const int t  = threadIdx.x;
  const int w  = t >> 6, l = t & 63;
  const int lr = l & 15, lg = l >> 4;
  const int wr = w >> 1, wc = w & 1;
  const int bn = blockIdx.x, bm = blockIdx.y;

  // staging: pass i covers rows i*32+srow of the 128x64 tile; source col
  // pre-swizzled so LDS stays linear and reads apply the same XOR.
  const int srow = t >> 3;                       // 0..31
  const int scol = 8 * ((t & 7) ^ (srow & 7));   // shorts

  const unsigned short* Ab = A  + (size_t)(bm * 128 + srow) * K + scol;
  const unsigned short* Bb = Bt + (size_t)(bn * 128 + srow) * K + scol;

  f32x4 acc[4][4];
#pragma unroll
  for (int m = 0; m < 4; ++m)
#pragma unroll
    for (int n = 0; n < 4; ++n)
      acc[m][n] = (f32x4){0.f, 0.f, 0.f, 0.f};

  for (int kt = 0; kt < K; kt += 64) {
#pragma unroll
    for (int i = 0; i < 4; ++i) {
      gload16(Ab + (size_t)i * 32 * K + kt, &As[(size_t)(i * 256 + t) * 8]);
      gload16(Bb + (size_t)i * 32 * K + kt, &Bs[(size_t)(i * 256 + t) * 8]);
    }
    __syncthreads();
#pragma unroll
    for (int ks = 0; ks < 2; ++ks) {
      short8 af[4], bf[4];
#pragma unroll
      for (int m = 0; m < 4; ++m) {
        int row = wr * 64 + m * 16 + lr;
        af[m] = *(const short8*)&As[row * 64 + ((ks * 32 + lg * 8) ^ ((row & 7) * 8))];
      }
#pragma unroll
      for (int n = 0; n < 4; ++n) {
        int row = wc * 64 + n * 16 + lr;
        bf[n] = *(const short8*)&Bs[row * 64 + ((ks * 32 + lg * 8) ^ ((row & 7) * 8))];
      }
#pragma unroll
      for (int m = 0; m < 4; ++m)
#pragma unroll
        for (int n = 0; n < 4; ++n)
          acc[m][n] = __builtin_amdgcn_mfma_f32_16x16x32_bf16(af[m], bf[n], acc[m][n], 0, 0, 0);
    }
    __syncthreads();
  }

#pragma unroll
  for (int m = 0; m < 4; ++m)
#pragma unroll
    for (int n = 0; n < 4; ++n)
#pragma unroll
      for (int r = 0; r < 4; ++r) {
        float v = acc[m][n][r];
        int i = bm * 128 + wr * 64 + m * 16 + lg * 4 + r;
        int j = bn * 128 + wc * 64 + n * 16 + lr;
        int b = i >> 11, s = i & 2047;
        int part = j >> 10, rem = j & 1023, h = rem >> 6, hd = rem & 63;
        size_t bh = (size_t)(b * H_ + h);
        if (part == 0) {
          // fold (1/sqrt(64)) * log2(e) so softmax uses native exp2
          qw[(bh * S_ + s) * HD_ + hd] = f2bf(v * 0.1803368801f);
        } else if (part == 1) {
          kw[(bh * S_ + s) * HD_ + hd] = f2bf(v);
        } else {
          // store V^T with pi-permuted column order within each 64-tile:
          // pi_inv(K) = (K&32) | ((K>>2)&3)<<3 | ((K>>4)&1)<<2 | (K&3)
          int s6 = s & 63;
          int sp = (s & ~63) | (s6 & 32) | (((s6 >> 2) & 3) << 3)
                 | (((s6 >> 4) & 1) << 2) | (s6 & 3);
          vTw[(bh * HD_ + hd) * S_ + sp] = f2bf(v);
        }
      }
}

// ---------------- out projection GEMM, 128x64 tile, BK=64, swizzled ----------------
// A[4096][1024] bf16 (attn), Bt[1024][1024] bf16 (w_out^T). out fp32 + bias.
__global__ __launch_bounds__(256)
void gemm_out(const unsigned short* __restrict__ A,
              const unsigned short* __restrict__ Bt,
              float* __restrict__ out,
              const float* __restrict__ bias) {
  const int K = 1024;
  __shared__ __align__(16) unsigned short As[128 * 64];
  __shared__ __align__(16) unsigned short Bs[64 * 64];
  const int t  = threadIdx.x;
  const int w  = t >> 6, l = t & 63;
  const int lr = l & 15, lg = l >> 4;
  const int wr = w >> 1, wc = w & 1;
  const int bn = blockIdx.x, bm = blockIdx.y;

  const int srow = t >> 3;
  const int scol = 8 * ((t & 7) ^ (srow & 7));

  const unsigned short* Ab = A  + (size_t)(bm * 128 + srow) * K + scol;
  const unsigned short* Bb = Bt + (size_t)(bn * 64 + srow) * K + scol;

  f32x4 acc[4][2];
#pragma unroll
  for (int m = 0; m < 4; ++m)
#pragma unroll
    for (int n = 0; n < 2; ++n)
      acc[m][n] = (f32x4){0.f, 0.f, 0.f, 0.f};

  for (int kt = 0; kt < K; kt += 64) {
#pragma unroll
    for (int i = 0; i < 4; ++i)
      gload16(Ab + (size_t)i * 32 * K + kt, &As[(size_t)(i * 256 + t) * 8]);
#pragma unroll
    for (int i = 0; i < 2; ++i)
      gload16(Bb + (size_t)i * 32 * K + kt, &Bs[(size_t)(i * 256 + t) * 8]);
    __syncthreads();
#pragma unroll
    for (int ks = 0; ks < 2; ++ks) {
      short8 af[4], bf[2];
#pragma unroll
      for (int m = 0; m < 4; ++m) {
        int row = wr * 64 + m * 16 + lr;
        af[m] = *(const short8*)&As[row * 64 + ((ks * 32 + lg * 8) ^ ((row & 7) * 8))];
      }
#pragma unroll
      for (int n = 0; n < 2; ++n) {
        int row = wc * 32 + n * 16 + lr;
        bf[n] = *(const short8*)&Bs[row * 64 + ((ks * 32 + lg * 8) ^ ((row & 7) * 8))];
      }
#pragma unroll
      for (int m = 0; m < 4; ++m)
#pragma unroll
        for (int n = 0; n < 2; ++n)
          acc[m][n] = __builtin_amdgcn_mfma_f32_16x16x32_bf16(af[m], bf[n], acc[m][n], 0, 0, 0);
    }
    __syncthreads();
  }

#pragma unroll
  for (int m = 0; m < 4; ++m)
#pragma unroll
    for (int n = 0; n < 2; ++n)
#pragma unroll
      for (int r = 0; r < 4; ++r) {
        int i = bm * 128 + wr * 64 + m * 16 + lg * 4 + r;
        int j = bn * 64 + wc * 32 + n * 16 + lr;
        out[(size_t)i * D_ + j] = acc[m][n][r] + bias[j];
      }
}

// ---------------- flash attention v5: raw-exp2 softmax ----------------
// 128 q-rows/block, 4 waves x 32 rows. K/V staged in LDS (dbuf, XOR-swizzled).
// S^T = mfma(K, Q) (Q pre-scaled by 0.125*log2e). V columns pre-pi-permuted so
// PV's B-frag is the lane-local packed P. Row-sums via mfma(ones, P).
__global__ __launch_bounds__(256)
void attn_kernel(const unsigned short* __restrict__ qw,
                 const unsigned short* __restrict__ kw,
                 const unsigned short* __restrict__ vTw,
                 unsigned short* __restrict__ attn) {
  __shared__ __align__(16) unsigned short Ks[2][KVT * 64];
  __shared__ __align__(16) unsigned short Vs[2][KVT * 64];

  const int t  = threadIdx.x;
  const int w  = t >> 6, l = t & 63;
  const int lr = l & 15, lg = l >> 4;
  const int blk = blockIdx.x;
  const int bh = blk >> 4, qt = blk & 15;
  const int q0 = qt * 128 + w * 32;
  const unsigned short* Qb = qw  + (size_t)bh * S_ * HD_;
  const unsigned short* Kb = kw  + (size_t)bh * S_ * HD_;
  const unsigned short* Vb = vTw + (size_t)bh * HD_ * S_;

  const int srow = t >> 3;                       // 0..31 within half-tile
  const int scol = 8 * ((t & 7) ^ (srow & 7));   // pre-swizzled source col (shorts)

  const short8 ones = {16256, 16256, 16256, 16256, 16256, 16256, 16256, 16256}; // bf16 1.0

  short8 qf[2][2];
#pragma unroll
  for (int m = 0; m < 2; ++m)
#pragma unroll
    for (int ks = 0; ks < 2; ++ks)
      qf[m][ks] = *(const short8*)&Qb[(size_t)(q0 + m * 16 + lr) * HD_ + ks * 32 + lg * 8];

  f32x4 of[2][4];               // O^T[d][q]: q=lr, d = nd*16+lg*4+r
  f32x4 osum[2];                // row-sum accumulator (replicated across regs/lg)
  float mrun[2];
#pragma unroll
  for (int m = 0; m < 2; ++m) {
#pragma unroll
    for (int n = 0; n < 4; ++n) of[m][n] = (f32x4){0.f, 0.f, 0.f, 0.f};
    osum[m] = (f32x4){0.f, 0.f, 0.f, 0.f};
    mrun[m] = -1e30f;
  }

  // prologue: stage tile 0 into buffer 0
#pragma unroll
  for (int i = 0; i < 2; ++i) {
    int row = i * 32 + srow;
    gload16(Kb + (size_t)row * HD_ + scol, &Ks[0][i * 2048 + t * 8]);
    gload16(Vb + (size_t)row * S_ + scol,  &Vs[0][i * 2048 + t * 8]);
  }
  __syncthreads();

  int cur = 0;
  for (int tt = 0; tt < NT; ++tt) {
    if (tt + 1 < NT) {
      const int kt = (tt + 1) * KVT;
#pragma unroll
      for (int i = 0; i < 2; ++i) {
        int row = i * 32 + srow;
        gload16(Kb + (size_t)(kt + row) * HD_ + scol, &Ks[cur ^ 1][i * 2048 + t * 8]);
        gload16(Vb + (size_t)row * S_ + kt + scol,    &Vs[cur ^ 1][i * 2048 + t * 8]);
      }
    }

    // ---- S^T = mfma(K, Q) : sfT[m][n] = S^T[k = n*16+lg*4+r][q = q0+m*16+lr] ----
    f32x4 sfT[2][4];
#pragma unroll
    for (int m = 0; m < 2; ++m)
#pragma unroll
      for (int n = 0; n < 4; ++n) sfT[m][n] = (f32x4){0.f, 0.f, 0.f, 0.f};
    __builtin_amdgcn_s_setprio(1);
#pragma unroll
    for (int ks = 0; ks < 2; ++ks) {
#pragma unroll
      for (int n = 0; n < 4; ++n) {
        int row = n * 16 + lr;
        short8 kf = *(const short8*)&Ks[cur][row * 64 + ((ks * 32 + lg * 8) ^ ((row & 7) * 8))];
        sfT[0][n] = __builtin_amdgcn_mfma_f32_16x16x32_bf16(kf, qf[0][ks], sfT[0][n], 0, 0, 0);
        sfT[1][n] = __builtin_amdgcn_mfma_f32_16x16x32_bf16(kf, qf[1][ks], sfT[1][n], 0, 0, 0);
      }
    }
    __builtin_amdgcn_s_setprio(0);

    // ---- softmax in log2 domain: tile max (tree), defer-max, raw exp2, pack ----
    float mx[2];
    bool need = false;
#pragma unroll
    for (int m = 0; m < 2; ++m) {
      float c0 = fmaxf(fmaxf(sfT[m][0][0], sfT[m][1][0]), fmaxf(sfT[m][2][0], sfT[m][3][0]));
      float c1 = fmaxf(fmaxf(sfT[m][0][1], sfT[m][1][1]), fmaxf(sfT[m][2][1], sfT[m][3][1]));
      float c2 = fmaxf(fmaxf(sfT[m][0][2], sfT[m][1][2]), fmaxf(sfT[m][2][2], sfT[m][3][2]));
      float c3 = fmaxf(fmaxf(sfT[m][0][3], sfT[m][1][3]), fmaxf(sfT[m][2][3], sfT[m][3][3]));
      float v = fmaxf(fmaxf(c0, c1), fmaxf(c2, c3));
      v = fmaxf(v, __shfl_xor(v, 16));
      v = fmaxf(v, __shfl_xor(v, 32));
      mx[m] = v;
      need = need || (v > mrun[m] + 10.0f);   // THR in log2 units
    }
    if (__any(need)) {
#pragma unroll
      for (int m = 0; m < 2; ++m) {
        float mn = fmaxf(mrun[m], mx[m]);
        float al = fexp2(mrun[m] - mn);
        mrun[m] = mn;
#pragma unroll
        for (int n = 0; n < 4; ++n)
#pragma unroll
          for (int r = 0; r < 4; ++r) of[m][n][r] *= al;
#pragma unroll
        for (int r = 0; r < 4; ++r) osum[m][r] *= al;
      }
    }
    uint32_t pk[2][4][2];
#pragma unroll
    for (int m = 0; m < 2; ++m) {
      float mm = mrun[m];
#pragma unroll
      for (int n = 0; n < 4; ++n) {
        float e0 = fexp2(sfT[m][n][0] - mm);
        float e1 = fexp2(sfT[m][n][1] - mm);
        float e2 = fexp2(sfT[m][n][2] - mm);
        float e3 = fexp2(sfT[m][n][3] - mm);
        pk[m][n][0] = cvtpk_bf16(e0, e1);
        pk[m][n][1] = cvtpk_bf16(e2, e3);
      }
    }

    // ---- O^T += V^T P^T and row-sums += 1 . P^T (all on MFMA pipe) ----
    union { uint32_t u[4]; short8 v; } pb[2][2];
#pragma unroll
    for (int m = 0; m < 2; ++m)
#pragma unroll
      for (int kk = 0; kk < 2; ++kk) {
        pb[m][kk].u[0] = pk[m][2 * kk][0];
        pb[m][kk].u[1] = pk[m][2 * kk][1];
        pb[m][kk].u[2] = pk[m][2 * kk + 1][0];
        pb[m][kk].u[3] = pk[m][2 * kk + 1][1];
      }
    __builtin_amdgcn_s_setprio(1);
#pragma unroll
    for (int nd = 0; nd < 4; ++nd)
#pragma unroll
      for (int kk = 0; kk < 2; ++kk) {
        int row = nd * 16 + lr;
        short8 vf = *(const short8*)&Vs[cur][row * 64 + ((kk * 32 + lg * 8) ^ ((row & 7) * 8))];
        of[0][nd] = __builtin_amdgcn_mfma_f32_16x16x32_bf16(vf, pb[0][kk].v, of[0][nd], 0, 0, 0);
        of[1][nd] = __builtin_amdgcn_mfma_f32_16x16x32_bf16(vf, pb[1][kk].v, of[1][nd], 0, 0, 0);
      }
#pragma unroll
    for (int m = 0; m < 2; ++m)
#pragma unroll
      for (int kk = 0; kk < 2; ++kk)
        osum[m] = __builtin_amdgcn_mfma_f32_16x16x32_bf16(ones, pb[m][kk].v, osum[m], 0, 0, 0);
    __builtin_amdgcn_s_setprio(0);

    __syncthreads();   // drains vmcnt (prefetch landed), barrier; swap
    cur ^= 1;
  }

  // finalize: osum[m][0] holds the full row sum (replicated); store O^T
  const int b = bh >> 4, h = bh & 15;
#pragma unroll
  for (int m = 0; m < 2; ++m) {
    float inv = 1.0f / osum[m][0];
    int q = q0 + m * 16 + lr;
#pragma unroll
    for (int nd = 0; nd < 4; ++nd)
#pragma unroll
      for (int r = 0; r < 4; ++r)
        attn[((size_t)b * S_ + q) * D_ + h * 64 + nd * 16 + lg * 4 + r] =
            f2bf(of[m][nd][r] * inv);
  }
}

extern "C" void kernel_launch(void* const* d_in, const int* in_sizes, int n_in,
                              void* d_out, int out_size, void* d_ws, size_t ws_size,
                              hipStream_t stream) {
  const float* x     = (const float*)d_in[0];
  const float* w_qkv = (const float*)d_in[1];
  const float* w_out = (const float*)d_in[2];
  const float* b_out = (const float*)d_in[3];
  float* out = (float*)d_out;

  char* p = (char*)d_ws;
  unsigned short* xb    = (unsigned short*)p; p += (size_t)4096 * 1024 * 2;        // 8 MiB
  unsigned short* wqkvT = (unsigned short*)p; p += (size_t)3072 * 1024 * 2;        // 6 MiB
  unsigned short* woutT = (unsigned short*)p; p += (size_t)1024 * 1024 * 2;        // 2 MiB
  unsigned short* qws   = (unsigned short*)p; p += (size_t)B_ * H_ * S_ * HD_ * 2; // 8 MiB
  unsigned short* kws   = (unsigned short*)p; p += (size_t)B_ * H_ * S_ * HD_ * 2; // 8 MiB
  unsigned short* vTws  = (unsigned short*)p; p += (size_t)B_ * H_ * S_ * HD_ * 2; // 8 MiB
  unsigned short* attnb = (unsigned short*)p; p += (size_t)4096 * 1024 * 2;        // 8 MiB

  // 1. casts / transposes
  cast_kernel<<<4096, 256, 0, stream>>>(x, xb, 4096 * 1024);
  dim3 tb(32, 8);
  transpose_cast_kernel<<<dim3(96, 32), tb, 0, stream>>>(w_qkv, wqkvT, 1024, 3072);
  transpose_cast_kernel<<<dim3(32, 32), tb, 0, stream>>>(w_out, woutT, 1024, 1024);

  // 2. QKV projection
  gemm_qkv<<<dim3(24, 32), 256, 0, stream>>>(xb, wqkvT, qws, kws, vTws);

  // 3. attention
  attn_kernel<<<512, 256, 0, stream>>>(qws, kws, vTws, attnb);

  // 4. output projection + bias (128x64 tiles -> 512 blocks, 2/CU)
  gemm_out<<<dim3(16, 32), 256, 0, stream>>>(attnb, woutT, out, b_out);
}

// Round 6
// 118.429 us; speedup vs baseline: 3.1546x; 1.0864x over previous
//
#include <hip/hip_runtime.h>
#include <stdint.h>

#define B_  2
#define S_  2048
#define D_  1024
#define H_  16
#define HD_ 64
#define KVT 128
#define NT  (S_ / KVT)   // 16 kv tiles

typedef __attribute__((ext_vector_type(8))) short short8;
typedef __attribute__((ext_vector_type(4))) float f32x4;

__device__ inline unsigned short f2bf(float f) {
  union { float f; unsigned int i; } u; u.f = f;
  unsigned int r = u.i + 0x7FFFu + ((u.i >> 16) & 1u);   // RNE
  return (unsigned short)(r >> 16);
}

__device__ inline uint32_t cvtpk_bf16(float lo, float hi) {
  uint32_t r;
  asm("v_cvt_pk_bf16_f32 %0, %1, %2" : "=v"(r) : "v"(lo), "v"(hi));
  return r;
}

// raw v_exp_f32 (2^x) — libm exp2f is a multi-inst correctly-rounded expansion
__device__ inline float fexp2(float x) {
  float r;
  asm("v_exp_f32 %0, %1" : "=v"(r) : "v"(x));
  return r;
}

__device__ inline void gload16(const void* g, void* l) {
  __builtin_amdgcn_global_load_lds(
      (const __attribute__((address_space(1))) void*)g,
      (__attribute__((address_space(3))) void*)l,
      16, 0, 0);
}

// ---------------- cast x (f32 -> bf16), vectorized x4 ----------------
__global__ void cast_kernel(const float* __restrict__ in,
                            unsigned short* __restrict__ out, int n) {
  int i = (blockIdx.x * blockDim.x + threadIdx.x) * 4;
  if (i >= n) return;
  float4 v = *(const float4*)(in + i);
  union { unsigned short s[4]; uint2 v; } o;
  o.s[0] = f2bf(v.x); o.s[1] = f2bf(v.y); o.s[2] = f2bf(v.z); o.s[3] = f2bf(v.w);
  *(uint2*)(out + i) = o.v;
}

// ---------------- transpose + cast: in[R][C] f32 -> out[C][R] bf16 ----------------
__global__ void transpose_cast_kernel(const float* __restrict__ in,
                                      unsigned short* __restrict__ out,
                                      int R, int C) {
  __shared__ float tile[32][33];
  int bx = blockIdx.x, by = blockIdx.y;
  int tx = threadIdx.x, ty = threadIdx.y;   // block (32,8)
#pragma unroll
  for (int i = 0; i < 4; ++i)
    tile[ty + i * 8][tx] = in[(size_t)(by * 32 + ty + i * 8) * C + bx * 32 + tx];
  __syncthreads();
#pragma unroll
  for (int i = 0; i < 4; ++i)
    out[(size_t)(bx * 32 + ty + i * 8) * R + by * 32 + tx] = f2bf(tile[tx][ty + i * 8]);
}

// ---------------- QKV GEMM, 128x128 tile, BK=64, XOR-swizzled LDS ----------------
// A[4096][1024] bf16, Bt[3072][1024] bf16. Epilogue:
//   q (pre-scaled by 0.125*log2e for exp2 softmax), k, vT (pi-permuted cols)
__global__ __launch_bounds__(256, 3)
void gemm_qkv(const unsigned short* __restrict__ A,
              const unsigned short* __restrict__ Bt,
              unsigned short* __restrict__ qw,
              unsigned short* __restrict__ kw,
              unsigned short* __restrict__ vTw) {
  const int K = 1024;
  __shared__ __align__(16) unsigned short As[128 * 64];
  __shared__ __align__(16) unsigned short Bs[128 * 64];
  const int t  = threadIdx.x;
  const int w  = t >> 6, l = t & 63;
  const int lr = l & 15, lg = l >> 4;
  const int wr = w >> 1, wc = w & 1;
  const int bn = blockIdx.x, bm = blockIdx.y;

  const int srow = t >> 3;                       // 0..31
  const int scol = 8 * ((t & 7) ^ (srow & 7));   // shorts

  const unsigned short* Ab = A  + (size_t)(bm * 128 + srow) * K + scol;
  const unsigned short* Bb = Bt + (size_t)(bn * 128 + srow) * K + scol;

  f32x4 acc[4][4];
#pragma unroll
  for (int m = 0; m < 4; ++m)
#pragma unroll
    for (int n = 0; n < 4; ++n)
      acc[m][n] = (f32x4){0.f, 0.f, 0.f, 0.f};

  for (int kt = 0; kt < K; kt += 64) {
#pragma unroll
    for (int i = 0; i < 4; ++i) {
      gload16(Ab + (size_t)i * 32 * K + kt, &As[(size_t)(i * 256 + t) * 8]);
      gload16(Bb + (size_t)i * 32 * K + kt, &Bs[(size_t)(i * 256 + t) * 8]);
    }
    __syncthreads();
#pragma unroll
    for (int ks = 0; ks < 2; ++ks) {
      short8 af[4], bf[4];
#pragma unroll
      for (int m = 0; m < 4; ++m) {
        int row = wr * 64 + m * 16 + lr;
        af[m] = *(const short8*)&As[row * 64 + ((ks * 32 + lg * 8) ^ ((row & 7) * 8))];
      }
#pragma unroll
      for (int n = 0; n < 4; ++n) {
        int row = wc * 64 + n * 16 + lr;
        bf[n] = *(const short8*)&Bs[row * 64 + ((ks * 32 + lg * 8) ^ ((row & 7) * 8))];
      }
#pragma unroll
      for (int m = 0; m < 4; ++m)
#pragma unroll
        for (int n = 0; n < 4; ++n)
          acc[m][n] = __builtin_amdgcn_mfma_f32_16x16x32_bf16(af[m], bf[n], acc[m][n], 0, 0, 0);
    }
    __syncthreads();
  }

#pragma unroll
  for (int m = 0; m < 4; ++m)
#pragma unroll
    for (int n = 0; n < 4; ++n)
#pragma unroll
      for (int r = 0; r < 4; ++r) {
        float v = acc[m][n][r];
        int i = bm * 128 + wr * 64 + m * 16 + lg * 4 + r;
        int j = bn * 128 + wc * 64 + n * 16 + lr;
        int b = i >> 11, s = i & 2047;
        int part = j >> 10, rem = j & 1023, h = rem >> 6, hd = rem & 63;
        size_t bh = (size_t)(b * H_ + h);
        if (part == 0) {
          // fold (1/sqrt(64)) * log2(e) so softmax uses native exp2
          qw[(bh * S_ + s) * HD_ + hd] = f2bf(v * 0.1803368801f);
        } else if (part == 1) {
          kw[(bh * S_ + s) * HD_ + hd] = f2bf(v);
        } else {
          // store V^T with pi-permuted column order within each 32-tile:
          // p = ((s6>>2)&3)*8 + ((s6>>4)&1)*4 + (s6&3), bit5 preserved
          int s6 = s & 63;
          int sp = (s & ~63) | (s6 & 32) | (((s6 >> 2) & 3) << 3)
                 | (((s6 >> 4) & 1) << 2) | (s6 & 3);
          vTw[(bh * HD_ + hd) * S_ + sp] = f2bf(v);
        }
      }
}

// ---------------- out projection GEMM, 128x64 tile, BK=64, swizzled ----------------
// A[4096][1024] bf16 (attn), Bt[1024][1024] bf16 (w_out^T). out fp32 + bias.
__global__ __launch_bounds__(256)
void gemm_out(const unsigned short* __restrict__ A,
              const unsigned short* __restrict__ Bt,
              float* __restrict__ out,
              const float* __restrict__ bias) {
  const int K = 1024;
  __shared__ __align__(16) unsigned short As[128 * 64];
  __shared__ __align__(16) unsigned short Bs[64 * 64];
  const int t  = threadIdx.x;
  const int w  = t >> 6, l = t & 63;
  const int lr = l & 15, lg = l >> 4;
  const int wr = w >> 1, wc = w & 1;
  const int bn = blockIdx.x, bm = blockIdx.y;

  const int srow = t >> 3;
  const int scol = 8 * ((t & 7) ^ (srow & 7));

  const unsigned short* Ab = A  + (size_t)(bm * 128 + srow) * K + scol;
  const unsigned short* Bb = Bt + (size_t)(bn * 64 + srow) * K + scol;

  f32x4 acc[4][2];
#pragma unroll
  for (int m = 0; m < 4; ++m)
#pragma unroll
    for (int n = 0; n < 2; ++n)
      acc[m][n] = (f32x4){0.f, 0.f, 0.f, 0.f};

  for (int kt = 0; kt < K; kt += 64) {
#pragma unroll
    for (int i = 0; i < 4; ++i)
      gload16(Ab + (size_t)i * 32 * K + kt, &As[(size_t)(i * 256 + t) * 8]);
#pragma unroll
    for (int i = 0; i < 2; ++i)
      gload16(Bb + (size_t)i * 32 * K + kt, &Bs[(size_t)(i * 256 + t) * 8]);
    __syncthreads();
#pragma unroll
    for (int ks = 0; ks < 2; ++ks) {
      short8 af[4], bf[2];
#pragma unroll
      for (int m = 0; m < 4; ++m) {
        int row = wr * 64 + m * 16 + lr;
        af[m] = *(const short8*)&As[row * 64 + ((ks * 32 + lg * 8) ^ ((row & 7) * 8))];
      }
#pragma unroll
      for (int n = 0; n < 2; ++n) {
        int row = wc * 32 + n * 16 + lr;
        bf[n] = *(const short8*)&Bs[row * 64 + ((ks * 32 + lg * 8) ^ ((row & 7) * 8))];
      }
#pragma unroll
      for (int m = 0; m < 4; ++m)
#pragma unroll
        for (int n = 0; n < 2; ++n)
          acc[m][n] = __builtin_amdgcn_mfma_f32_16x16x32_bf16(af[m], bf[n], acc[m][n], 0, 0, 0);
    }
    __syncthreads();
  }

#pragma unroll
  for (int m = 0; m < 4; ++m)
#pragma unroll
    for (int n = 0; n < 2; ++n)
#pragma unroll
      for (int r = 0; r < 4; ++r) {
        int i = bm * 128 + wr * 64 + m * 16 + lg * 4 + r;
        int j = bn * 64 + wc * 32 + n * 16 + lr;
        out[(size_t)i * D_ + j] = acc[m][n][r] + bias[j];
      }
}

// ---------------- flash attention v6: KVT=128, XCD swizzle ----------------
// 128 q-rows/block, 4 waves x 32 rows. K/V staged in LDS (dbuf, XOR-swizzled).
// S^T = mfma(K, Q) (Q pre-scaled by 0.125*log2e). V columns pre-pi-permuted so
// PV's B-frag is the lane-local packed P. Row-sums via mfma(ones, P).
__global__ __launch_bounds__(256, 2)
void attn_kernel(const unsigned short* __restrict__ qw,
                 const unsigned short* __restrict__ kw,
                 const unsigned short* __restrict__ vTw,
                 unsigned short* __restrict__ attn) {
  __shared__ __align__(16) unsigned short Ks[2][KVT * 64];   // [128 s][64 hd]
  __shared__ __align__(16) unsigned short Vs[2][64 * KVT];   // [64 hd][128 s]

  const int t  = threadIdx.x;
  const int w  = t >> 6, l = t & 63;
  const int lr = l & 15, lg = l >> 4;

  // XCD-aware block swizzle: all 16 q-tiles of one (b,h) land on one XCD
  const int bid = blockIdx.x;
  const int bh = (bid & 7) * 4 + ((bid >> 3) & 3);
  const int qt = bid >> 5;

  const int q0 = qt * 128 + w * 32;
  const unsigned short* Qb = qw  + (size_t)bh * S_ * HD_;
  const unsigned short* Kb = kw  + (size_t)bh * S_ * HD_;
  const unsigned short* Vb = vTw + (size_t)bh * HD_ * S_;

  // staging geometry (pre-swizzled source cols, linear LDS dest):
  // K tile [128][64]: 8 granules/row; V tile [64][128]: 16 granules/row
  const int krow = t >> 3, kcol = 8 * ((t & 7) ^ ((t >> 3) & 7));
  const int vrow = t >> 4, vcol = 8 * ((t & 15) ^ ((t >> 4) & 7));

  const short8 ones = {16256, 16256, 16256, 16256, 16256, 16256, 16256, 16256}; // bf16 1.0
  const f32x4 FZERO = (f32x4){0.f, 0.f, 0.f, 0.f};

  short8 qf[2][2];
#pragma unroll
  for (int m = 0; m < 2; ++m)
#pragma unroll
    for (int ks = 0; ks < 2; ++ks)
      qf[m][ks] = *(const short8*)&Qb[(size_t)(q0 + m * 16 + lr) * HD_ + ks * 32 + lg * 8];

  f32x4 of[2][4];               // O^T[d][q]: q=lr, d = nd*16+lg*4+r
  f32x4 osum[2];                // row-sum accumulator (replicated across regs/lg)
  float mrun[2];
#pragma unroll
  for (int m = 0; m < 2; ++m) {
#pragma unroll
    for (int n = 0; n < 4; ++n) of[m][n] = FZERO;
    osum[m] = FZERO;
    mrun[m] = -1e30f;
  }

  // prologue: stage tile 0 into buffer 0
#pragma unroll
  for (int i = 0; i < 4; ++i) {
    gload16(Kb + (size_t)(i * 32 + krow) * HD_ + kcol, &Ks[0][(i * 256 + t) * 8]);
    gload16(Vb + (size_t)(i * 16 + vrow) * S_ + vcol,  &Vs[0][(i * 256 + t) * 8]);
  }
  __syncthreads();

  int cur = 0;
  for (int tt = 0; tt < NT; ++tt) {
    if (tt + 1 < NT) {
      const int kt = (tt + 1) * KVT;
#pragma unroll
      for (int i = 0; i < 4; ++i) {
        gload16(Kb + (size_t)(kt + i * 32 + krow) * HD_ + kcol, &Ks[cur ^ 1][(i * 256 + t) * 8]);
        gload16(Vb + (size_t)(i * 16 + vrow) * S_ + kt + vcol,  &Vs[cur ^ 1][(i * 256 + t) * 8]);
      }
    }

    // ---- S^T = mfma(K, Q) : sfT[m][n] = S^T[k = n*16+lg*4+r][q = q0+m*16+lr] ----
    f32x4 sfT[2][8];
    __builtin_amdgcn_s_setprio(1);
#pragma unroll
    for (int n = 0; n < 8; ++n) {
      int row = n * 16 + lr;
      short8 kf0 = *(const short8*)&Ks[cur][row * 64 + ((lg * 8) ^ ((row & 7) * 8))];
      sfT[0][n] = __builtin_amdgcn_mfma_f32_16x16x32_bf16(kf0, qf[0][0], FZERO, 0, 0, 0);
      sfT[1][n] = __builtin_amdgcn_mfma_f32_16x16x32_bf16(kf0, qf[1][0], FZERO, 0, 0, 0);
      short8 kf1 = *(const short8*)&Ks[cur][row * 64 + ((32 + lg * 8) ^ ((row & 7) * 8))];
      sfT[0][n] = __builtin_amdgcn_mfma_f32_16x16x32_bf16(kf1, qf[0][1], sfT[0][n], 0, 0, 0);
      sfT[1][n] = __builtin_amdgcn_mfma_f32_16x16x32_bf16(kf1, qf[1][1], sfT[1][n], 0, 0, 0);
    }
    __builtin_amdgcn_s_setprio(0);

    // ---- softmax in log2 domain: tile max (tree), defer-max, raw exp2 ----
    float mx[2];
    bool need = false;
#pragma unroll
    for (int m = 0; m < 2; ++m) {
      f32x4 cm = sfT[m][0];
#pragma unroll
      for (int n = 1; n < 8; ++n) {
        cm[0] = fmaxf(cm[0], sfT[m][n][0]);
        cm[1] = fmaxf(cm[1], sfT[m][n][1]);
        cm[2] = fmaxf(cm[2], sfT[m][n][2]);
        cm[3] = fmaxf(cm[3], sfT[m][n][3]);
      }
      float v = fmaxf(fmaxf(cm[0], cm[1]), fmaxf(cm[2], cm[3]));
      v = fmaxf(v, __shfl_xor(v, 16));
      v = fmaxf(v, __shfl_xor(v, 32));
      mx[m] = v;
      need = need || (v > mrun[m] + 10.0f);   // THR in log2 units
    }
    if (__any(need)) {
#pragma unroll
      for (int m = 0; m < 2; ++m) {
        float mn = fmaxf(mrun[m], mx[m]);
        float al = fexp2(mrun[m] - mn);
        mrun[m] = mn;
#pragma unroll
        for (int n = 0; n < 4; ++n)
#pragma unroll
          for (int r = 0; r < 4; ++r) of[m][n][r] *= al;
#pragma unroll
        for (int r = 0; r < 4; ++r) osum[m][r] *= al;
      }
    }
    // exp in place, then pack straight into PV B-fragments
    union { uint32_t u[4]; short8 v; } pb[2][4];
#pragma unroll
    for (int m = 0; m < 2; ++m) {
      float mm = mrun[m];
#pragma unroll
      for (int n = 0; n < 8; ++n) {
        sfT[m][n][0] = fexp2(sfT[m][n][0] - mm);
        sfT[m][n][1] = fexp2(sfT[m][n][1] - mm);
        sfT[m][n][2] = fexp2(sfT[m][n][2] - mm);
        sfT[m][n][3] = fexp2(sfT[m][n][3] - mm);
      }
#pragma unroll
      for (int kk = 0; kk < 4; ++kk) {
        pb[m][kk].u[0] = cvtpk_bf16(sfT[m][2 * kk][0],     sfT[m][2 * kk][1]);
        pb[m][kk].u[1] = cvtpk_bf16(sfT[m][2 * kk][2],     sfT[m][2 * kk][3]);
        pb[m][kk].u[2] = cvtpk_bf16(sfT[m][2 * kk + 1][0], sfT[m][2 * kk + 1][1]);
        pb[m][kk].u[3] = cvtpk_bf16(sfT[m][2 * kk + 1][2], sfT[m][2 * kk + 1][3]);
      }
    }

    // ---- O^T += V^T P^T and row-sums += 1 . P^T (all on MFMA pipe) ----
    __builtin_amdgcn_s_setprio(1);
#pragma unroll
    for (int nd = 0; nd < 4; ++nd)
#pragma unroll
      for (int kk = 0; kk < 4; ++kk) {
        int row = nd * 16 + lr;
        short8 vf = *(const short8*)&Vs[cur][row * 128 + ((kk * 32 + lg * 8) ^ ((row & 7) * 8))];
        of[0][nd] = __builtin_amdgcn_mfma_f32_16x16x32_bf16(vf, pb[0][kk].v, of[0][nd], 0, 0, 0);
        of[1][nd] = __builtin_amdgcn_mfma_f32_16x16x32_bf16(vf, pb[1][kk].v, of[1][nd], 0, 0, 0);
      }
#pragma unroll
    for (int m = 0; m < 2; ++m)
#pragma unroll
      for (int kk = 0; kk < 4; ++kk)
        osum[m] = __builtin_amdgcn_mfma_f32_16x16x32_bf16(ones, pb[m][kk].v, osum[m], 0, 0, 0);
    __builtin_amdgcn_s_setprio(0);

    __syncthreads();   // drains vmcnt (prefetch landed), barrier; swap
    cur ^= 1;
  }

  // finalize: osum[m][0] holds the full row sum (replicated); store O^T
  const int b = bh >> 4, h = bh & 15;
#pragma unroll
  for (int m = 0; m < 2; ++m) {
    float inv = 1.0f / osum[m][0];
    int q = q0 + m * 16 + lr;
#pragma unroll
    for (int nd = 0; nd < 4; ++nd)
#pragma unroll
      for (int r = 0; r < 4; ++r)
        attn[((size_t)b * S_ + q) * D_ + h * 64 + nd * 16 + lg * 4 + r] =
            f2bf(of[m][nd][r] * inv);
  }
}

extern "C" void kernel_launch(void* const* d_in, const int* in_sizes, int n_in,
                              void* d_out, int out_size, void* d_ws, size_t ws_size,
                              hipStream_t stream) {
  const float* x     = (const float*)d_in[0];
  const float* w_qkv = (const float*)d_in[1];
  const float* w_out = (const float*)d_in[2];
  const float* b_out = (const float*)d_in[3];
  float* out = (float*)d_out;

  char* p = (char*)d_ws;
  unsigned short* xb    = (unsigned short*)p; p += (size_t)4096 * 1024 * 2;        // 8 MiB
  unsigned short* wqkvT = (unsigned short*)p; p += (size_t)3072 * 1024 * 2;        // 6 MiB
  unsigned short* woutT = (unsigned short*)p; p += (size_t)1024 * 1024 * 2;        // 2 MiB
  unsigned short* qws   = (unsigned short*)p; p += (size_t)B_ * H_ * S_ * HD_ * 2; // 8 MiB
  unsigned short* kws   = (unsigned short*)p; p += (size_t)B_ * H_ * S_ * HD_ * 2; // 8 MiB
  unsigned short* vTws  = (unsigned short*)p; p += (size_t)B_ * H_ * S_ * HD_ * 2; // 8 MiB
  unsigned short* attnb = (unsigned short*)p; p += (size_t)4096 * 1024 * 2;        // 8 MiB

  // 1. casts / transposes
  cast_kernel<<<4096, 256, 0, stream>>>(x, xb, 4096 * 1024);
  dim3 tb(32, 8);
  transpose_cast_kernel<<<dim3(96, 32), tb, 0, stream>>>(w_qkv, wqkvT, 1024, 3072);
  transpose_cast_kernel<<<dim3(32, 32), tb, 0, stream>>>(w_out, woutT, 1024, 1024);

  // 2. QKV projection
  gemm_qkv<<<dim3(24, 32), 256, 0, stream>>>(xb, wqkvT, qws, kws, vTws);

  // 3. attention
  attn_kernel<<<512, 256, 0, stream>>>(qws, kws, vTws, attnb);

  // 4. output projection + bias (128x64 tiles -> 512 blocks, 2/CU)
  gemm_out<<<dim3(16, 32), 256, 0, stream>>>(attnb, woutT, out, b_out);
}